// Round 18
// baseline (148.101 us; speedup 1.0000x reference)
//
#include <hip/hip_runtime.h>

#define B_ 4
#define S_ 2048
#define D_ 768
#define H_ 12
#define HD_ 64
#define T_ (B_ * S_)  // 8192

typedef __bf16 bf16x8 __attribute__((ext_vector_type(8)));
typedef __bf16 bf16x4 __attribute__((ext_vector_type(4)));
typedef float  f32x4  __attribute__((ext_vector_type(4)));

__device__ __forceinline__ f32x4 mfma16(bf16x8 a, bf16x8 b, f32x4 c) {
  return __builtin_amdgcn_mfma_f32_16x16x32_bf16(a, b, c, 0, 0, 0);
}

// 2^x via v_exp_f32 (scores are pre-scaled by log2e at weight-convert time)
__device__ __forceinline__ float fexp2(float x) {
  float r;
  asm("v_exp_f32 %0, %1" : "=v"(r) : "v"(x));
  return r;
}

// async global->LDS, 16B per lane. LDS dest is wave-uniform base + lane*16.
__device__ __forceinline__ void gload16(const __bf16* g, __bf16* lds) {
  __builtin_amdgcn_global_load_lds(
      (__attribute__((address_space(1))) void*)g,
      (__attribute__((address_space(3))) void*)lds, 16, 0, 0);
}

// ---------------- fused fp32 -> bf16 convert (x + 4 weights, 1 launch) -------
__global__ void cvt_all(const float* __restrict__ x,
                        const float* __restrict__ wq,
                        const float* __restrict__ wk,
                        const float* __restrict__ wv,
                        const float* __restrict__ wo,
                        __bf16* __restrict__ out) {
  constexpr int XN4 = T_ * D_ / 4;
  constexpr int WN4 = D_ * D_ / 4;
  const int i = blockIdx.x * blockDim.x + threadIdx.x;
  if (i >= XN4 + 4 * WN4) return;
  const float* src;
  int k;
  float scale = 1.0f;
  if (i < XN4) {
    src = x;
    k = i;
  } else {
    const int j = i - XN4;
    const int wsel = j / WN4;
    k = j - wsel * WN4;
    src = (wsel == 0) ? wq : (wsel == 1) ? wk : (wsel == 2) ? wv : wo;
    if (wsel == 1) scale = 0.18033688f;  // 0.125 * log2(e)
  }
  const float4 v = reinterpret_cast<const float4*>(src)[k];
  bf16x4 o;
  o[0] = (__bf16)(v.x * scale);
  o[1] = (__bf16)(v.y * scale);
  o[2] = (__bf16)(v.z * scale);
  o[3] = (__bf16)(v.w * scale);
  reinterpret_cast<bf16x4*>(out)[i] = o;
}

// ---------------- GEMM: C[m][n] = sum_k A[m][k] * W[n][k]  (B^T layout) ------
// r16-exact (passed, best): 128x128, BK=64, 2-deep counted-vmcnt, swizzled
// LDS, XCD-slab remap, vectorized V^T epilogue.
template <int MODE>
__global__ __launch_bounds__(256)
__attribute__((amdgpu_waves_per_eu(2)))
void gemm_bt(const __bf16* __restrict__ A,
             const __bf16* __restrict__ W0, const __bf16* __restrict__ W1,
             const __bf16* __restrict__ W2,
             __bf16* __restrict__ Oq, __bf16* __restrict__ Ok,
             __bf16* __restrict__ Ov,
             float* __restrict__ fout, const float* __restrict__ bias) {
  constexpr int K = D_;       // 768
  constexpr int NT = K / 64;  // 12 K-tiles
  __shared__ __align__(16) __bf16 sA[2][128 * 64];
  __shared__ __align__(16) __bf16 sB[2][128 * 64];

  const int tid = threadIdx.x;
  const int l = tid & 63;
  const int w = tid >> 6;

  const int flat = blockIdx.y * 64 + blockIdx.x;
  const int xcd = flat & 7;
  const int q = flat >> 3;
  const int mtile = xcd * 8 + (q & 7);
  const int pan = q >> 3;
  const int m0 = mtile * 128;

  int mat, n0;
  const __bf16* Wm;
  if (MODE == 0) {
    mat = pan / 6;
    n0 = (pan % 6) * 128;
    Wm = (mat == 0) ? W0 : (mat == 1) ? W1 : W2;
  } else {
    mat = 0;
    n0 = pan * 128;
    Wm = W0;
  }

  const int srow = l >> 3;                // 0..7
  const int scol = ((l & 7) ^ srow) * 8;  // source col (elements)
  const __bf16* gA[4];
  const __bf16* gB[4];
#pragma unroll
  for (int i = 0; i < 4; ++i) {
    const int c = w * 4 + i;
    gA[i] = A + (size_t)(m0 + c * 8 + srow) * K + scol;
    gB[i] = Wm + (size_t)(n0 + c * 8 + srow) * K + scol;
  }

  f32x4 acc[4][4] = {};
  const int wr = w >> 1, wc = w & 1;
  const int fr = l & 15, fq = l >> 4;
  const int swz = (fr & 7) << 4;

#pragma unroll
  for (int i = 0; i < 4; ++i) {
    const int c = w * 4 + i;
    gload16(gA[i], &sA[0][c * 512]);
    gload16(gB[i], &sB[0][c * 512]);
  }
#pragma unroll
  for (int i = 0; i < 4; ++i) {
    const int c = w * 4 + i;
    gload16(gA[i] + 64, &sA[1][c * 512]);
    gload16(gB[i] + 64, &sB[1][c * 512]);
  }

  int cur = 0;
  for (int kt = 0; kt < NT; ++kt) {
    if (kt + 1 < NT)
      asm volatile("s_waitcnt vmcnt(8)" ::: "memory");
    else
      asm volatile("s_waitcnt vmcnt(0)" ::: "memory");
    __builtin_amdgcn_s_barrier();

    const char* ab = reinterpret_cast<const char*>(&sA[cur][0]);
    const char* bb = reinterpret_cast<const char*>(&sB[cur][0]);
#pragma unroll
    for (int ks = 0; ks < 2; ++ks) {
      bf16x8 af[4], bfr[4];
#pragma unroll
      for (int mi = 0; mi < 4; ++mi)
        af[mi] = *reinterpret_cast<const bf16x8*>(
            ab + (wr * 64 + mi * 16 + fr) * 128 +
            ((ks * 64 + fq * 16) ^ swz));
#pragma unroll
      for (int ni = 0; ni < 4; ++ni)
        bfr[ni] = *reinterpret_cast<const bf16x8*>(
            bb + (wc * 64 + ni * 16 + fr) * 128 +
            ((ks * 64 + fq * 16) ^ swz));
#pragma unroll
      for (int mi = 0; mi < 4; ++mi)
#pragma unroll
        for (int ni = 0; ni < 4; ++ni)
          acc[mi][ni] = mfma16(af[mi], bfr[ni], acc[mi][ni]);
    }
    __builtin_amdgcn_s_barrier();

    if (kt + 2 < NT) {
      const int ko = (kt + 2) * 64;
#pragma unroll
      for (int i = 0; i < 4; ++i) {
        const int c = w * 4 + i;
        gload16(gA[i] + ko, &sA[cur][c * 512]);
        gload16(gB[i] + ko, &sB[cur][c * 512]);
      }
    }
    cur ^= 1;
  }

#pragma unroll
  for (int mi = 0; mi < 4; ++mi) {
    const int mbase = m0 + wr * 64 + mi * 16 + fq * 4;
#pragma unroll
    for (int ni = 0; ni < 4; ++ni) {
      const int o = n0 + wc * 64 + ni * 16 + fr;
      if (MODE == 1) {
#pragma unroll
        for (int r = 0; r < 4; ++r)
          fout[(mbase + r) * D_ + o] = acc[mi][ni][r] + bias[o];
      } else {
        const int h = o >> 6, hd = o & 63;
        const int b = mbase >> 11, s = mbase & (S_ - 1);
        if (mat == 2) {
          bf16x4 vv;
#pragma unroll
          for (int r = 0; r < 4; ++r) vv[r] = (__bf16)acc[mi][ni][r];
          *reinterpret_cast<bf16x4*>(
              &Ov[((size_t)((b * H_ + h) * HD_ + hd)) * S_ + s]) = vv;
        } else {
          __bf16* dst = (mat == 0) ? Oq : Ok;
#pragma unroll
          for (int r = 0; r < 4; ++r)
            dst[((size_t)((b * H_ + h) * S_ + s + r)) * HD_ + hd] =
                (__bf16)acc[mi][ni][r];
        }
      }
    }
  }
}

// ---------------- causal flash attention: K staged, V direct from L2 ----------
// r18: r9-r17's attn staged BOTH K and V via global_load_lds. The r11-r17
// null results + m97 arithmetic converge on a ~20-25 GB/s/CU gload_lds fill
// ceiling shared with the GEMMs (attn: 209 MB staged / 68 us = 12 GB/s/CU,
// tile-time 2.1 us = 3 blk x 16 KB / supply). Fix: stage only K (shared,
// swizzle-needed); read V^T directly per-warp from L2 (6 heads/XCD keeps V
// L2-resident; vector-load path, not the fill path). Staging demand halves;
// LDS 48->32 KB. V fragments hoisted right after QK^T (r8 pattern, shared by
// both q-groups, live only across softmax; +32 VGPR, budget OK at (3,4)).
__global__ __launch_bounds__(256)
__attribute__((amdgpu_waves_per_eu(3, 4)))
void attn_kernel(const __bf16* __restrict__ Q, const __bf16* __restrict__ Kt,
                 const __bf16* __restrict__ Vt, __bf16* __restrict__ C) {
  __shared__ __align__(16) __bf16 sK[2][64 * 64];  // [kv][hd], swizzled
  __shared__ __align__(16) __bf16 sP[4][32 * 64];  // per-warp P, swizzled

  const int tid = threadIdx.x;
  const int l = tid & 63;
  const int w = tid >> 6;
  const int fr = l & 15, fq = l >> 4;
  const int bx = blockIdx.x;
  const int xcd = bx & 7;
  const int j = bx >> 3;   // [0, 96)
  const int L = j >> 5;    // dispatch layer 0,1,2
  const int u = j & 31;
  const int i = u & 15;
  const int rep = u >> 4;
  int qtile;
  if (L == 0) qtile = 15 - i;
  else if (L == 1) qtile = (i < 8) ? 2 * i : 2 * i - 15;
  else qtile = (i < 8) ? 7 - i : 23 - i;
  const int bh = xcd + 8 * (2 * L + rep);  // head in [0,48), 6 per XCD
  const int qb = qtile * 128;
  const int qbw = qb + w * 32;  // this warp's 32 q-rows

  const __bf16* qh = Q + (size_t)bh * S_ * HD_;
  const __bf16* kh = Kt + (size_t)bh * S_ * HD_;
  const __bf16* vh = Vt + (size_t)bh * HD_ * S_;
  char* sPb = reinterpret_cast<char*>(&sP[w][0]);

  const int srow = l >> 3;                       // 0..7
  const int scol = ((l & 7) * 8) ^ (srow << 3);  // pre-swizzled source col
  const int swz = (fr & 7) << 4;                 // read-side XOR (bytes)

  bf16x8 qf[2][2];
#pragma unroll
  for (int g = 0; g < 2; ++g)
#pragma unroll
    for (int ks = 0; ks < 2; ++ks)
      qf[g][ks] = *reinterpret_cast<const bf16x8*>(
          &qh[(size_t)(qbw + g * 16 + fr) * HD_ + ks * 32 + fq * 8]);

  f32x4 acc[2][4] = {};
  float mrow[2] = {-1e30f, -1e30f}, lrow[2] = {0.f, 0.f};

  const int nt = qb / 64 + 2;  // = 2*qtile + 2 >= 2
  int cur = 0;
  const int q0 = 2 * w, q1 = 2 * w + 1;

  // prologue: stage K tiles 0 and 1 (2 loads/wave each; 4 in flight)
  gload16(kh + (size_t)(q0 * 8 + srow) * HD_ + scol, &sK[0][q0 * 512]);
  gload16(kh + (size_t)(q1 * 8 + srow) * HD_ + scol, &sK[0][q1 * 512]);
  gload16(kh + (size_t)(64 + q0 * 8 + srow) * HD_ + scol, &sK[1][q0 * 512]);
  gload16(kh + (size_t)(64 + q1 * 8 + srow) * HD_ + scol, &sK[1][q1 * 512]);

  for (int t = 0; t < nt; ++t) {
    // wait own K-stage(t) only; stage(t+1) stays in flight
    if (t + 1 < nt)
      asm volatile("s_waitcnt vmcnt(2)" ::: "memory");
    else
      asm volatile("s_waitcnt vmcnt(0)" ::: "memory");
    __builtin_amdgcn_s_barrier();  // all warps' K-stage(t) landed

    const int kv0 = t * 64;
    if (kv0 <= qbw + 31) {
      const char* kb = reinterpret_cast<const char*>(&sK[cur][0]);

      f32x4 s[2][4];
      __builtin_amdgcn_s_setprio(1);
#pragma unroll
      for (int c = 0; c < 4; ++c) {
        const int row = c * 16 + fr;
        bf16x8 kf0 = *reinterpret_cast<const bf16x8*>(
            kb + row * 128 + ((fq * 16) ^ swz));
        bf16x8 kf1 = *reinterpret_cast<const bf16x8*>(
            kb + row * 128 + ((fq * 16 + 64) ^ swz));
#pragma unroll
        for (int g = 0; g < 2; ++g) {
          f32x4 z = {};
          z = mfma16(kf0, qf[g][0], z);
          z = mfma16(kf1, qf[g][1], z);
          s[g][c] = z;
        }
      }
      __builtin_amdgcn_s_setprio(0);

      // issue ALL V loads now (L2-resident; shared by both q-groups).
      // Latency hides under mask + softmax; live range ends at PV.
      bf16x8 vf[4][2];
#pragma unroll
      for (int dt = 0; dt < 4; ++dt) {
        vf[dt][0] = *reinterpret_cast<const bf16x8*>(
            &vh[(size_t)(dt * 16 + fr) * S_ + kv0 + fq * 8]);
        vf[dt][1] = *reinterpret_cast<const bf16x8*>(
            &vh[(size_t)(dt * 16 + fr) * S_ + kv0 + 32 + fq * 8]);
      }

      if (kv0 + 63 > qbw) {
#pragma unroll
        for (int g = 0; g < 2; ++g) {
          const int qi = qbw + g * 16 + fr;
#pragma unroll
          for (int c = 0; c < 4; ++c)
#pragma unroll
            for (int r = 0; r < 4; ++r) {
              const int kvi = kv0 + c * 16 + fq * 4 + r;
              if (kvi > qi) s[g][c][r] = -1e30f;
            }
        }
      }

#pragma unroll
      for (int g = 0; g < 2; ++g) {
        float tm = -1e30f;
#pragma unroll
        for (int c = 0; c < 4; ++c)
#pragma unroll
          for (int r = 0; r < 4; ++r) tm = fmaxf(tm, s[g][c][r]);
        tm = fmaxf(tm, __shfl_xor(tm, 16));
        tm = fmaxf(tm, __shfl_xor(tm, 32));
        // defer-max (T13): skip rescale while max grows < 8 (log2-domain)
        const bool defer = __all(tm - mrow[g] <= 8.0f);
        const float mn = defer ? mrow[g] : fmaxf(mrow[g], tm);
        if (!defer) {
          const float fac = fexp2(mrow[g] - mn);
          mrow[g] = mn;
          lrow[g] *= fac;
#pragma unroll
          for (int dt = 0; dt < 4; ++dt)
#pragma unroll
            for (int r = 0; r < 4; ++r) acc[g][dt][r] *= fac;
        }
        float sum = 0.f;
#pragma unroll
        for (int c = 0; c < 4; ++c) {
          bf16x4 pc;
#pragma unroll
          for (int r = 0; r < 4; ++r) {
            const float p = fexp2(s[g][c][r] - mn);
            sum += p;
            pc[r] = (__bf16)p;
          }
          const int bo = (c * 32 + fq * 8) ^ swz;
          *reinterpret_cast<bf16x4*>(sPb + (g * 16 + fr) * 128 + bo) = pc;
        }
        sum += __shfl_xor(sum, 16);
        sum += __shfl_xor(sum, 32);
        lrow[g] += sum;

        bf16x8 pa[2];
#pragma unroll
        for (int ks = 0; ks < 2; ++ks) {
          const int bo = (ks * 64 + fq * 16) ^ swz;
          pa[ks] = *reinterpret_cast<const bf16x8*>(sPb +
                                                    (g * 16 + fr) * 128 + bo);
        }

        __builtin_amdgcn_s_setprio(1);
#pragma unroll
        for (int dt = 0; dt < 4; ++dt) {
          acc[g][dt] = mfma16(vf[dt][0], pa[0], acc[g][dt]);
          acc[g][dt] = mfma16(vf[dt][1], pa[1], acc[g][dt]);
        }
        __builtin_amdgcn_s_setprio(0);
      }
    }

    __builtin_amdgcn_s_barrier();  // all warps done reading sK[cur]

    // stage K tile t+2 into the buffer just freed
    if (t + 2 < nt) {
      const int kvn = (t + 2) * 64;
      gload16(kh + (size_t)(kvn + q0 * 8 + srow) * HD_ + scol,
              &sK[cur][q0 * 512]);
      gload16(kh + (size_t)(kvn + q1 * 8 + srow) * HD_ + scol,
              &sK[cur][q1 * 512]);
    }
    cur ^= 1;
  }

  const int b = bh / H_, h = bh % H_;
#pragma unroll
  for (int g = 0; g < 2; ++g) {
    const float inv_l = 1.0f / lrow[g];
    const int qrow = qbw + g * 16 + fr;
#pragma unroll
    for (int dt = 0; dt < 4; ++dt) {
      bf16x4 ov;
#pragma unroll
      for (int r = 0; r < 4; ++r) ov[r] = (__bf16)(acc[g][dt][r] * inv_l);
      *reinterpret_cast<bf16x4*>(
          &C[((size_t)(b * S_ + qrow)) * D_ + h * HD_ + dt * 16 + fq * 4]) =
          ov;
    }
  }
}

// ---------------- workspace layout (bf16 elements) ---------------------------
static constexpr size_t XB_OFF = 0;
static constexpr size_t WQ_OFF = XB_OFF + (size_t)T_ * D_;
static constexpr size_t WK_OFF = WQ_OFF + (size_t)D_ * D_;
static constexpr size_t WV_OFF = WK_OFF + (size_t)D_ * D_;
static constexpr size_t WO_OFF = WV_OFF + (size_t)D_ * D_;
static constexpr size_t Q_OFF = WO_OFF + (size_t)D_ * D_;
static constexpr size_t K_OFF = Q_OFF + (size_t)T_ * D_;
static constexpr size_t V_OFF = K_OFF + (size_t)T_ * D_;
static constexpr size_t C_OFF = V_OFF + (size_t)T_ * D_;

extern "C" void kernel_launch(void* const* d_in, const int* in_sizes, int n_in,
                              void* d_out, int out_size, void* d_ws,
                              size_t ws_size, hipStream_t stream) {
  const float* x = (const float*)d_in[0];
  const float* wq = (const float*)d_in[1];
  const float* wk = (const float*)d_in[2];
  const float* wv = (const float*)d_in[3];
  const float* wo = (const float*)d_in[4];
  const float* bo = (const float*)d_in[5];
  float* out = (float*)d_out;
  __bf16* ws = (__bf16*)d_ws;

  __bf16* xb = ws + XB_OFF;
  __bf16* wqb = ws + WQ_OFF;
  __bf16* wkb = ws + WK_OFF;
  __bf16* wvb = ws + WV_OFF;
  __bf16* wob = ws + WO_OFF;
  __bf16* qbuf = ws + Q_OFF;
  __bf16* kbuf = ws + K_OFF;
  __bf16* vbuf = ws + V_OFF;
  __bf16* cbuf = ws + C_OFF;

  {
    constexpr int n4 = T_ * D_ / 4 + 4 * (D_ * D_ / 4);
    cvt_all<<<(n4 + 255) / 256, 256, 0, stream>>>(x, wq, wk, wv, wo, ws);
  }

  gemm_bt<0><<<dim3(64, 18), 256, 0, stream>>>(
      xb, wqb, wkb, wvb, qbuf, kbuf, vbuf, nullptr, nullptr);

  attn_kernel<<<dim3(768), 256, 0, stream>>>(qbuf, kbuf, vbuf, cbuf);

  gemm_bt<1><<<dim3(64, 6), 256, 0, stream>>>(
      cbuf, wob, nullptr, nullptr, nullptr, nullptr, nullptr, out, bo);
}

// Round 19
// 128.608 us; speedup vs baseline: 1.1516x; 1.1516x over previous
//
#include <hip/hip_runtime.h>

#define B_ 4
#define S_ 2048
#define D_ 768
#define H_ 12
#define HD_ 64
#define T_ (B_ * S_)  // 8192

typedef __bf16 bf16x8 __attribute__((ext_vector_type(8)));
typedef __bf16 bf16x4 __attribute__((ext_vector_type(4)));
typedef float  f32x4  __attribute__((ext_vector_type(4)));

__device__ __forceinline__ f32x4 mfma16(bf16x8 a, bf16x8 b, f32x4 c) {
  return __builtin_amdgcn_mfma_f32_16x16x32_bf16(a, b, c, 0, 0, 0);
}

// 2^x via v_exp_f32 (scores are pre-scaled by log2e at weight-convert time)
__device__ __forceinline__ float fexp2(float x) {
  float r;
  asm("v_exp_f32 %0, %1" : "=v"(r) : "v"(x));
  return r;
}

// async global->LDS, 16B per lane. LDS dest is wave-uniform base + lane*16.
__device__ __forceinline__ void gload16(const __bf16* g, __bf16* lds) {
  __builtin_amdgcn_global_load_lds(
      (__attribute__((address_space(1))) void*)g,
      (__attribute__((address_space(3))) void*)lds, 16, 0, 0);
}

// ---------------- fused fp32 -> bf16 convert (x + 4 weights, 1 launch) -------
__global__ void cvt_all(const float* __restrict__ x,
                        const float* __restrict__ wq,
                        const float* __restrict__ wk,
                        const float* __restrict__ wv,
                        const float* __restrict__ wo,
                        __bf16* __restrict__ out) {
  constexpr int XN4 = T_ * D_ / 4;
  constexpr int WN4 = D_ * D_ / 4;
  const int i = blockIdx.x * blockDim.x + threadIdx.x;
  if (i >= XN4 + 4 * WN4) return;
  const float* src;
  int k;
  float scale = 1.0f;
  if (i < XN4) {
    src = x;
    k = i;
  } else {
    const int j = i - XN4;
    const int wsel = j / WN4;
    k = j - wsel * WN4;
    src = (wsel == 0) ? wq : (wsel == 1) ? wk : (wsel == 2) ? wv : wo;
    if (wsel == 1) scale = 0.18033688f;  // 0.125 * log2(e)
  }
  const float4 v = reinterpret_cast<const float4*>(src)[k];
  bf16x4 o;
  o[0] = (__bf16)(v.x * scale);
  o[1] = (__bf16)(v.y * scale);
  o[2] = (__bf16)(v.z * scale);
  o[3] = (__bf16)(v.w * scale);
  reinterpret_cast<bf16x4*>(out)[i] = o;
}

// ---------------- GEMM: C[m][n] = sum_k A[m][k] * W[n][k]  (B^T layout) ------
// r16-exact (passed, best): 128x128, BK=64, 2-deep counted-vmcnt, swizzled
// LDS, XCD-slab remap, vectorized V^T epilogue.
template <int MODE>
__global__ __launch_bounds__(256)
__attribute__((amdgpu_waves_per_eu(2)))
void gemm_bt(const __bf16* __restrict__ A,
             const __bf16* __restrict__ W0, const __bf16* __restrict__ W1,
             const __bf16* __restrict__ W2,
             __bf16* __restrict__ Oq, __bf16* __restrict__ Ok,
             __bf16* __restrict__ Ov,
             float* __restrict__ fout, const float* __restrict__ bias) {
  constexpr int K = D_;       // 768
  constexpr int NT = K / 64;  // 12 K-tiles
  __shared__ __align__(16) __bf16 sA[2][128 * 64];
  __shared__ __align__(16) __bf16 sB[2][128 * 64];

  const int tid = threadIdx.x;
  const int l = tid & 63;
  const int w = tid >> 6;

  const int flat = blockIdx.y * 64 + blockIdx.x;
  const int xcd = flat & 7;
  const int q = flat >> 3;
  const int mtile = xcd * 8 + (q & 7);
  const int pan = q >> 3;
  const int m0 = mtile * 128;

  int mat, n0;
  const __bf16* Wm;
  if (MODE == 0) {
    mat = pan / 6;
    n0 = (pan % 6) * 128;
    Wm = (mat == 0) ? W0 : (mat == 1) ? W1 : W2;
  } else {
    mat = 0;
    n0 = pan * 128;
    Wm = W0;
  }

  const int srow = l >> 3;                // 0..7
  const int scol = ((l & 7) ^ srow) * 8;  // source col (elements)
  const __bf16* gA[4];
  const __bf16* gB[4];
#pragma unroll
  for (int i = 0; i < 4; ++i) {
    const int c = w * 4 + i;
    gA[i] = A + (size_t)(m0 + c * 8 + srow) * K + scol;
    gB[i] = Wm + (size_t)(n0 + c * 8 + srow) * K + scol;
  }

  f32x4 acc[4][4] = {};
  const int wr = w >> 1, wc = w & 1;
  const int fr = l & 15, fq = l >> 4;
  const int swz = (fr & 7) << 4;

#pragma unroll
  for (int i = 0; i < 4; ++i) {
    const int c = w * 4 + i;
    gload16(gA[i], &sA[0][c * 512]);
    gload16(gB[i], &sB[0][c * 512]);
  }
#pragma unroll
  for (int i = 0; i < 4; ++i) {
    const int c = w * 4 + i;
    gload16(gA[i] + 64, &sA[1][c * 512]);
    gload16(gB[i] + 64, &sB[1][c * 512]);
  }

  int cur = 0;
  for (int kt = 0; kt < NT; ++kt) {
    if (kt + 1 < NT)
      asm volatile("s_waitcnt vmcnt(8)" ::: "memory");
    else
      asm volatile("s_waitcnt vmcnt(0)" ::: "memory");
    __builtin_amdgcn_s_barrier();

    const char* ab = reinterpret_cast<const char*>(&sA[cur][0]);
    const char* bb = reinterpret_cast<const char*>(&sB[cur][0]);
#pragma unroll
    for (int ks = 0; ks < 2; ++ks) {
      bf16x8 af[4], bfr[4];
#pragma unroll
      for (int mi = 0; mi < 4; ++mi)
        af[mi] = *reinterpret_cast<const bf16x8*>(
            ab + (wr * 64 + mi * 16 + fr) * 128 +
            ((ks * 64 + fq * 16) ^ swz));
#pragma unroll
      for (int ni = 0; ni < 4; ++ni)
        bfr[ni] = *reinterpret_cast<const bf16x8*>(
            bb + (wc * 64 + ni * 16 + fr) * 128 +
            ((ks * 64 + fq * 16) ^ swz));
#pragma unroll
      for (int mi = 0; mi < 4; ++mi)
#pragma unroll
        for (int ni = 0; ni < 4; ++ni)
          acc[mi][ni] = mfma16(af[mi], bfr[ni], acc[mi][ni]);
    }
    __builtin_amdgcn_s_barrier();

    if (kt + 2 < NT) {
      const int ko = (kt + 2) * 64;
#pragma unroll
      for (int i = 0; i < 4; ++i) {
        const int c = w * 4 + i;
        gload16(gA[i] + ko, &sA[cur][c * 512]);
        gload16(gB[i] + ko, &sB[cur][c * 512]);
      }
    }
    cur ^= 1;
  }

#pragma unroll
  for (int mi = 0; mi < 4; ++mi) {
    const int mbase = m0 + wr * 64 + mi * 16 + fq * 4;
#pragma unroll
    for (int ni = 0; ni < 4; ++ni) {
      const int o = n0 + wc * 64 + ni * 16 + fr;
      if (MODE == 1) {
#pragma unroll
        for (int r = 0; r < 4; ++r)
          fout[(mbase + r) * D_ + o] = acc[mi][ni][r] + bias[o];
      } else {
        const int h = o >> 6, hd = o & 63;
        const int b = mbase >> 11, s = mbase & (S_ - 1);
        if (mat == 2) {
          bf16x4 vv;
#pragma unroll
          for (int r = 0; r < 4; ++r) vv[r] = (__bf16)acc[mi][ni][r];
          *reinterpret_cast<bf16x4*>(
              &Ov[((size_t)((b * H_ + h) * HD_ + hd)) * S_ + s]) = vv;
        } else {
          __bf16* dst = (mat == 0) ? Oq : Ok;
#pragma unroll
          for (int r = 0; r < 4; ++r)
            dst[((size_t)((b * H_ + h) * S_ + s + r)) * HD_ + hd] =
                (__bf16)acc[mi][ni][r];
        }
      }
    }
  }
}

// ---------------- causal flash attention: 4-warp block, LDS-staged K/V --------
// r16-exact structure (sK + sV staged, stage-t+1-then-compute, one barrier
// per tile). r19 change (only): OPTIMISTIC softmax — for t>0, exp2(s - m_old)
// is issued immediately (m_old wave-synced from prior tile), overlapping the
// max-tree + 2 __shfl_xor (LDS-pipe, ~100cy each) that previously gated every
// exp. Wave-uniform defer check (T13): common case skips acc-rescale; rare
// growth case scales p/acc/lrow by exp2(m_old - m_new) (exact). Tile 0 keeps
// the ordered path (m_old = -1e30 would overflow the optimistic exp).
__global__ __launch_bounds__(256)
__attribute__((amdgpu_waves_per_eu(3, 4)))
void attn_kernel(const __bf16* __restrict__ Q, const __bf16* __restrict__ Kt,
                 const __bf16* __restrict__ Vt, __bf16* __restrict__ C) {
  __shared__ __align__(16) __bf16 sK[2][64 * 64];  // [kv][hd], swizzled
  __shared__ __align__(16) __bf16 sV[2][64 * 64];  // V^T [hd][kv], swizzled
  __shared__ __align__(16) __bf16 sP[4][32 * 64];  // per-warp P, swizzled

  const int tid = threadIdx.x;
  const int l = tid & 63;
  const int w = tid >> 6;
  const int fr = l & 15, fq = l >> 4;
  const int bx = blockIdx.x;
  const int xcd = bx & 7;
  const int j = bx >> 3;             // [0, 96)
  const int bh = xcd + 8 * (j % 6);  // head in [0, 48)
  const int qtile = 15 - j / 6;      // [0, 16), deep first
  const int qb = qtile * 128;
  const int qbw = qb + w * 32;  // this warp's 32 q-rows

  const __bf16* qh = Q + (size_t)bh * S_ * HD_;
  const __bf16* kh = Kt + (size_t)bh * S_ * HD_;
  const __bf16* vh = Vt + (size_t)bh * HD_ * S_;
  char* sPb = reinterpret_cast<char*>(&sP[w][0]);

  const int srow = l >> 3;                       // 0..7
  const int scol = ((l & 7) * 8) ^ (srow << 3);  // pre-swizzled source col
  const int swz = (fr & 7) << 4;                 // read-side XOR (bytes)

  bf16x8 qf[2][2];
#pragma unroll
  for (int g = 0; g < 2; ++g)
#pragma unroll
    for (int ks = 0; ks < 2; ++ks)
      qf[g][ks] = *reinterpret_cast<const bf16x8*>(
          &qh[(size_t)(qbw + g * 16 + fr) * HD_ + ks * 32 + fq * 8]);

  f32x4 acc[2][4] = {};
  float mrow[2] = {-1e30f, -1e30f}, lrow[2] = {0.f, 0.f};

  const int nt = qb / 64 + 2;  // ceil((qb+128)/64)
  int cur = 0;

  {
    const int q0 = 2 * w, q1 = 2 * w + 1;
    gload16(kh + (size_t)(q0 * 8 + srow) * HD_ + scol, &sK[0][q0 * 512]);
    gload16(kh + (size_t)(q1 * 8 + srow) * HD_ + scol, &sK[0][q1 * 512]);
    gload16(vh + (size_t)(q0 * 8 + srow) * S_ + scol, &sV[0][q0 * 512]);
    gload16(vh + (size_t)(q1 * 8 + srow) * S_ + scol, &sV[0][q1 * 512]);
  }
  __syncthreads();

  for (int t = 0; t < nt; ++t) {
    const int kv0 = t * 64;
    if (t + 1 < nt) {
      const int kvn = kv0 + 64;
      const int q0 = 2 * w, q1 = 2 * w + 1;
      gload16(kh + (size_t)(kvn + q0 * 8 + srow) * HD_ + scol,
              &sK[cur ^ 1][q0 * 512]);
      gload16(kh + (size_t)(kvn + q1 * 8 + srow) * HD_ + scol,
              &sK[cur ^ 1][q1 * 512]);
      gload16(vh + (size_t)(q0 * 8 + srow) * S_ + kvn + scol,
              &sV[cur ^ 1][q0 * 512]);
      gload16(vh + (size_t)(q1 * 8 + srow) * S_ + kvn + scol,
              &sV[cur ^ 1][q1 * 512]);
    }

    if (kv0 <= qbw + 31) {
      const char* kb = reinterpret_cast<const char*>(&sK[cur][0]);
      const char* vb = reinterpret_cast<const char*>(&sV[cur][0]);

      f32x4 s[2][4];
      __builtin_amdgcn_s_setprio(1);
#pragma unroll
      for (int c = 0; c < 4; ++c) {
        const int row = c * 16 + fr;
        bf16x8 kf0 = *reinterpret_cast<const bf16x8*>(
            kb + row * 128 + ((fq * 16) ^ swz));
        bf16x8 kf1 = *reinterpret_cast<const bf16x8*>(
            kb + row * 128 + ((fq * 16 + 64) ^ swz));
#pragma unroll
        for (int g = 0; g < 2; ++g) {
          f32x4 z = {};
          z = mfma16(kf0, qf[g][0], z);
          z = mfma16(kf1, qf[g][1], z);
          s[g][c] = z;
        }
      }
      __builtin_amdgcn_s_setprio(0);

      if (kv0 + 63 > qbw) {
#pragma unroll
        for (int g = 0; g < 2; ++g) {
          const int qi = qbw + g * 16 + fr;
#pragma unroll
          for (int c = 0; c < 4; ++c)
#pragma unroll
            for (int r = 0; r < 4; ++r) {
              const int kvi = kv0 + c * 16 + fq * 4 + r;
              if (kvi > qi) s[g][c][r] = -1e30f;
            }
        }
      }

#pragma unroll
      for (int g = 0; g < 2; ++g) {
        // lane-local max tree (no cross-lane yet)
        float tm = -1e30f;
#pragma unroll
        for (int c = 0; c < 4; ++c)
#pragma unroll
          for (int r = 0; r < 4; ++r) tm = fmaxf(tm, s[g][c][r]);

        if (t == 0) {
          // ordered path (mrow = -1e30 would overflow optimistic exp)
          tm = fmaxf(tm, __shfl_xor(tm, 16));
          tm = fmaxf(tm, __shfl_xor(tm, 32));
          mrow[g] = tm;
          float sum = 0.f;
#pragma unroll
          for (int c = 0; c < 4; ++c) {
            bf16x4 pc;
#pragma unroll
            for (int r = 0; r < 4; ++r) {
              const float p = fexp2(s[g][c][r] - tm);
              sum += p;
              pc[r] = (__bf16)p;
            }
            const int bo = (c * 32 + fq * 8) ^ swz;
            *reinterpret_cast<bf16x4*>(sPb + (g * 16 + fr) * 128 + bo) = pc;
          }
          sum += __shfl_xor(sum, 16);
          sum += __shfl_xor(sum, 32);
          lrow[g] = sum;
        } else {
          // optimistic: exp with m_old (wave-synced) overlaps the shfl chain
          const float mb = mrow[g];
          float tmx = fmaxf(tm, __shfl_xor(tm, 16));   // LDS-pipe latency...
          tmx = fmaxf(tmx, __shfl_xor(tmx, 32));
#pragma unroll
          for (int c = 0; c < 4; ++c)                  // ...hidden by exps
#pragma unroll
            for (int r = 0; r < 4; ++r)
              s[g][c][r] = fexp2(s[g][c][r] - mb);
          float fac = 1.0f;
          if (!__all(tmx - mb <= 8.0f)) {  // rare: real max growth
            const float mn = fmaxf(mb, tmx);
            fac = fexp2(mb - mn);  // 1.0 for rows that didn't grow
            mrow[g] = mn;
            lrow[g] *= fac;
#pragma unroll
            for (int dt = 0; dt < 4; ++dt)
#pragma unroll
              for (int r = 0; r < 4; ++r) acc[g][dt][r] *= fac;
          }
          float sum = 0.f;
#pragma unroll
          for (int c = 0; c < 4; ++c) {
            bf16x4 pc;
#pragma unroll
            for (int r = 0; r < 4; ++r) {
              const float p = s[g][c][r] * fac;
              sum += p;
              pc[r] = (__bf16)p;
            }
            const int bo = (c * 32 + fq * 8) ^ swz;
            *reinterpret_cast<bf16x4*>(sPb + (g * 16 + fr) * 128 + bo) = pc;
          }
          sum += __shfl_xor(sum, 16);
          sum += __shfl_xor(sum, 32);
          lrow[g] += sum;
        }

        bf16x8 pa[2];
#pragma unroll
        for (int ks = 0; ks < 2; ++ks) {
          const int bo = (ks * 64 + fq * 16) ^ swz;
          pa[ks] = *reinterpret_cast<const bf16x8*>(sPb +
                                                    (g * 16 + fr) * 128 + bo);
        }

        __builtin_amdgcn_s_setprio(1);
#pragma unroll
        for (int dt = 0; dt < 4; ++dt) {
          const int row = dt * 16 + fr;
          bf16x8 vf0 = *reinterpret_cast<const bf16x8*>(
              vb + row * 128 + ((fq * 16) ^ swz));
          bf16x8 vf1 = *reinterpret_cast<const bf16x8*>(
              vb + row * 128 + ((fq * 16 + 64) ^ swz));
          acc[g][dt] = mfma16(vf0, pa[0], acc[g][dt]);
          acc[g][dt] = mfma16(vf1, pa[1], acc[g][dt]);
        }
        __builtin_amdgcn_s_setprio(0);
      }
    }

    __syncthreads();
    cur ^= 1;
  }

  const int b = bh / H_, h = bh % H_;
#pragma unroll
  for (int g = 0; g < 2; ++g) {
    const float inv_l = 1.0f / lrow[g];
    const int qrow = qbw + g * 16 + fr;
#pragma unroll
    for (int dt = 0; dt < 4; ++dt) {
      bf16x4 ov;
#pragma unroll
      for (int r = 0; r < 4; ++r) ov[r] = (__bf16)(acc[g][dt][r] * inv_l);
      *reinterpret_cast<bf16x4*>(
          &C[((size_t)(b * S_ + qrow)) * D_ + h * HD_ + dt * 16 + fq * 4]) =
          ov;
    }
  }
}

// ---------------- workspace layout (bf16 elements) ---------------------------
static constexpr size_t XB_OFF = 0;
static constexpr size_t WQ_OFF = XB_OFF + (size_t)T_ * D_;
static constexpr size_t WK_OFF = WQ_OFF + (size_t)D_ * D_;
static constexpr size_t WV_OFF = WK_OFF + (size_t)D_ * D_;
static constexpr size_t WO_OFF = WV_OFF + (size_t)D_ * D_;
static constexpr size_t Q_OFF = WO_OFF + (size_t)D_ * D_;
static constexpr size_t K_OFF = Q_OFF + (size_t)T_ * D_;
static constexpr size_t V_OFF = K_OFF + (size_t)T_ * D_;
static constexpr size_t C_OFF = V_OFF + (size_t)T_ * D_;

extern "C" void kernel_launch(void* const* d_in, const int* in_sizes, int n_in,
                              void* d_out, int out_size, void* d_ws,
                              size_t ws_size, hipStream_t stream) {
  const float* x = (const float*)d_in[0];
  const float* wq = (const float*)d_in[1];
  const float* wk = (const float*)d_in[2];
  const float* wv = (const float*)d_in[3];
  const float* wo = (const float*)d_in[4];
  const float* bo = (const float*)d_in[5];
  float* out = (float*)d_out;
  __bf16* ws = (__bf16*)d_ws;

  __bf16* xb = ws + XB_OFF;
  __bf16* wqb = ws + WQ_OFF;
  __bf16* wkb = ws + WK_OFF;
  __bf16* wvb = ws + WV_OFF;
  __bf16* wob = ws + WO_OFF;
  __bf16* qbuf = ws + Q_OFF;
  __bf16* kbuf = ws + K_OFF;
  __bf16* vbuf = ws + V_OFF;
  __bf16* cbuf = ws + C_OFF;

  {
    constexpr int n4 = T_ * D_ / 4 + 4 * (D_ * D_ / 4);
    cvt_all<<<(n4 + 255) / 256, 256, 0, stream>>>(x, wq, wk, wv, wo, ws);
  }

  gemm_bt<0><<<dim3(64, 18), 256, 0, stream>>>(
      xb, wqb, wkb, wvb, qbuf, kbuf, vbuf, nullptr, nullptr);

  attn_kernel<<<dim3(768), 256, 0, stream>>>(qbuf, kbuf, vbuf, cbuf);

  gemm_bt<1><<<dim3(64, 6), 256, 0, stream>>>(
      cbuf, wob, nullptr, nullptr, nullptr, nullptr, nullptr, out, bo);
}

// Round 20
// 121.325 us; speedup vs baseline: 1.2207x; 1.0600x over previous
//
#include <hip/hip_runtime.h>

#define B_ 4
#define S_ 2048
#define D_ 768
#define H_ 12
#define HD_ 64
#define T_ (B_ * S_)  // 8192

typedef __bf16 bf16x8 __attribute__((ext_vector_type(8)));
typedef __bf16 bf16x4 __attribute__((ext_vector_type(4)));
typedef float  f32x4  __attribute__((ext_vector_type(4)));

__device__ __forceinline__ f32x4 mfma16(bf16x8 a, bf16x8 b, f32x4 c) {
  return __builtin_amdgcn_mfma_f32_16x16x32_bf16(a, b, c, 0, 0, 0);
}

// 2^x via v_exp_f32 (scores are pre-scaled by log2e at weight-convert time)
__device__ __forceinline__ float fexp2(float x) {
  float r;
  asm("v_exp_f32 %0, %1" : "=v"(r) : "v"(x));
  return r;
}

// async global->LDS, 16B per lane. LDS dest is wave-uniform base + lane*16.
__device__ __forceinline__ void gload16(const __bf16* g, __bf16* lds) {
  __builtin_amdgcn_global_load_lds(
      (__attribute__((address_space(1))) void*)g,
      (__attribute__((address_space(3))) void*)lds, 16, 0, 0);
}

// ---------------- fused fp32 -> bf16 convert (x + 4 weights, 1 launch) -------
__global__ void cvt_all(const float* __restrict__ x,
                        const float* __restrict__ wq,
                        const float* __restrict__ wk,
                        const float* __restrict__ wv,
                        const float* __restrict__ wo,
                        __bf16* __restrict__ out) {
  constexpr int XN4 = T_ * D_ / 4;
  constexpr int WN4 = D_ * D_ / 4;
  const int i = blockIdx.x * blockDim.x + threadIdx.x;
  if (i >= XN4 + 4 * WN4) return;
  const float* src;
  int k;
  float scale = 1.0f;
  if (i < XN4) {
    src = x;
    k = i;
  } else {
    const int j = i - XN4;
    const int wsel = j / WN4;
    k = j - wsel * WN4;
    src = (wsel == 0) ? wq : (wsel == 1) ? wk : (wsel == 2) ? wv : wo;
    if (wsel == 1) scale = 0.18033688f;  // 0.125 * log2(e)
  }
  const float4 v = reinterpret_cast<const float4*>(src)[k];
  bf16x4 o;
  o[0] = (__bf16)(v.x * scale);
  o[1] = (__bf16)(v.y * scale);
  o[2] = (__bf16)(v.z * scale);
  o[3] = (__bf16)(v.w * scale);
  reinterpret_cast<bf16x4*>(out)[i] = o;
}

// ---------------- GEMM: C[m][n] = sum_k A[m][k] * W[n][k]  (B^T layout) ------
// r16-exact (passed, best): 128x128, BK=64, 2-deep counted-vmcnt, swizzled
// LDS, XCD-slab remap, vectorized V^T epilogue.
template <int MODE>
__global__ __launch_bounds__(256)
__attribute__((amdgpu_waves_per_eu(2)))
void gemm_bt(const __bf16* __restrict__ A,
             const __bf16* __restrict__ W0, const __bf16* __restrict__ W1,
             const __bf16* __restrict__ W2,
             __bf16* __restrict__ Oq, __bf16* __restrict__ Ok,
             __bf16* __restrict__ Ov,
             float* __restrict__ fout, const float* __restrict__ bias) {
  constexpr int K = D_;       // 768
  constexpr int NT = K / 64;  // 12 K-tiles
  __shared__ __align__(16) __bf16 sA[2][128 * 64];
  __shared__ __align__(16) __bf16 sB[2][128 * 64];

  const int tid = threadIdx.x;
  const int l = tid & 63;
  const int w = tid >> 6;

  const int flat = blockIdx.y * 64 + blockIdx.x;
  const int xcd = flat & 7;
  const int q = flat >> 3;
  const int mtile = xcd * 8 + (q & 7);
  const int pan = q >> 3;
  const int m0 = mtile * 128;

  int mat, n0;
  const __bf16* Wm;
  if (MODE == 0) {
    mat = pan / 6;
    n0 = (pan % 6) * 128;
    Wm = (mat == 0) ? W0 : (mat == 1) ? W1 : W2;
  } else {
    mat = 0;
    n0 = pan * 128;
    Wm = W0;
  }

  const int srow = l >> 3;                // 0..7
  const int scol = ((l & 7) ^ srow) * 8;  // source col (elements)
  const __bf16* gA[4];
  const __bf16* gB[4];
#pragma unroll
  for (int i = 0; i < 4; ++i) {
    const int c = w * 4 + i;
    gA[i] = A + (size_t)(m0 + c * 8 + srow) * K + scol;
    gB[i] = Wm + (size_t)(n0 + c * 8 + srow) * K + scol;
  }

  f32x4 acc[4][4] = {};
  const int wr = w >> 1, wc = w & 1;
  const int fr = l & 15, fq = l >> 4;
  const int swz = (fr & 7) << 4;

#pragma unroll
  for (int i = 0; i < 4; ++i) {
    const int c = w * 4 + i;
    gload16(gA[i], &sA[0][c * 512]);
    gload16(gB[i], &sB[0][c * 512]);
  }
#pragma unroll
  for (int i = 0; i < 4; ++i) {
    const int c = w * 4 + i;
    gload16(gA[i] + 64, &sA[1][c * 512]);
    gload16(gB[i] + 64, &sB[1][c * 512]);
  }

  int cur = 0;
  for (int kt = 0; kt < NT; ++kt) {
    if (kt + 1 < NT)
      asm volatile("s_waitcnt vmcnt(8)" ::: "memory");
    else
      asm volatile("s_waitcnt vmcnt(0)" ::: "memory");
    __builtin_amdgcn_s_barrier();

    const char* ab = reinterpret_cast<const char*>(&sA[cur][0]);
    const char* bb = reinterpret_cast<const char*>(&sB[cur][0]);
#pragma unroll
    for (int ks = 0; ks < 2; ++ks) {
      bf16x8 af[4], bfr[4];
#pragma unroll
      for (int mi = 0; mi < 4; ++mi)
        af[mi] = *reinterpret_cast<const bf16x8*>(
            ab + (wr * 64 + mi * 16 + fr) * 128 +
            ((ks * 64 + fq * 16) ^ swz));
#pragma unroll
      for (int ni = 0; ni < 4; ++ni)
        bfr[ni] = *reinterpret_cast<const bf16x8*>(
            bb + (wc * 64 + ni * 16 + fr) * 128 +
            ((ks * 64 + fq * 16) ^ swz));
#pragma unroll
      for (int mi = 0; mi < 4; ++mi)
#pragma unroll
        for (int ni = 0; ni < 4; ++ni)
          acc[mi][ni] = mfma16(af[mi], bfr[ni], acc[mi][ni]);
    }
    __builtin_amdgcn_s_barrier();

    if (kt + 2 < NT) {
      const int ko = (kt + 2) * 64;
#pragma unroll
      for (int i = 0; i < 4; ++i) {
        const int c = w * 4 + i;
        gload16(gA[i] + ko, &sA[cur][c * 512]);
        gload16(gB[i] + ko, &sB[cur][c * 512]);
      }
    }
    cur ^= 1;
  }

#pragma unroll
  for (int mi = 0; mi < 4; ++mi) {
    const int mbase = m0 + wr * 64 + mi * 16 + fq * 4;
#pragma unroll
    for (int ni = 0; ni < 4; ++ni) {
      const int o = n0 + wc * 64 + ni * 16 + fr;
      if (MODE == 1) {
#pragma unroll
        for (int r = 0; r < 4; ++r)
          fout[(mbase + r) * D_ + o] = acc[mi][ni][r] + bias[o];
      } else {
        const int h = o >> 6, hd = o & 63;
        const int b = mbase >> 11, s = mbase & (S_ - 1);
        if (mat == 2) {
          bf16x4 vv;
#pragma unroll
          for (int r = 0; r < 4; ++r) vv[r] = (__bf16)acc[mi][ni][r];
          *reinterpret_cast<bf16x4*>(
              &Ov[((size_t)((b * H_ + h) * HD_ + hd)) * S_ + s]) = vv;
        } else {
          __bf16* dst = (mat == 0) ? Oq : Ok;
#pragma unroll
          for (int r = 0; r < 4; ++r)
            dst[((size_t)((b * H_ + h) * S_ + s + r)) * HD_ + hd] =
                (__bf16)acc[mi][ni][r];
        }
      }
    }
  }
}

// ---------------- causal flash attention: 64-q blocks, 4 waves/SIMD -----------
// r20: r16-r19 attn was GRID-capped at 3 blocks/CU (768 = 3x256 exactly, no
// backfill); SIMD issue was 53% idle (VALU 35 + MFMA 15). attn staged only
// 3.1 TB/s vs gemm0's demonstrated 10.3 TB/s gload_lds supply -> staging has
// headroom. Fix: 64 q-rows/block (4 warps x 16), grid = 32 qtiles x 48 heads
// = 1536 blocks; LDS 40 KB -> 4 blocks/CU resident + 2 queued (backfill).
// Staging doubles (405 MB ~ 40 GB/s/CU, at the demonstrated ceiling); issue
// per wave halves. Same swapped-QK + LDS K/V structure, one barrier per tile.
__global__ __launch_bounds__(256)
__attribute__((amdgpu_waves_per_eu(4, 4)))
void attn_kernel(const __bf16* __restrict__ Q, const __bf16* __restrict__ Kt,
                 const __bf16* __restrict__ Vt, __bf16* __restrict__ C) {
  __shared__ __align__(16) __bf16 sK[2][64 * 64];  // [kv][hd], swizzled
  __shared__ __align__(16) __bf16 sV[2][64 * 64];  // V^T [hd][kv], swizzled
  __shared__ __align__(16) __bf16 sP[4][16 * 64];  // per-warp P (2 KB)

  const int tid = threadIdx.x;
  const int l = tid & 63;
  const int w = tid >> 6;
  const int fr = l & 15, fq = l >> 4;
  const int bx = blockIdx.x;
  const int xcd = bx & 7;
  const int j = bx >> 3;             // [0, 192)
  const int bh = xcd + 8 * (j % 6);  // head in [0, 48), 6 per XCD
  const int qtile = 31 - j / 6;      // [0, 32), deep first
  const int qb = qtile * 64;
  const int qbw = qb + w * 16;  // this warp's 16 q-rows

  const __bf16* qh = Q + (size_t)bh * S_ * HD_;
  const __bf16* kh = Kt + (size_t)bh * S_ * HD_;
  const __bf16* vh = Vt + (size_t)bh * HD_ * S_;
  char* sPb = reinterpret_cast<char*>(&sP[w][0]);

  const int srow = l >> 3;                       // 0..7
  const int scol = ((l & 7) * 8) ^ (srow << 3);  // pre-swizzled source col
  const int swz = (fr & 7) << 4;                 // read-side XOR (bytes)

  // Q fragment (B-operand): q = qbw + fr, k = ks*32 + fq*8 ..
  bf16x8 qf[2];
#pragma unroll
  for (int ks = 0; ks < 2; ++ks)
    qf[ks] = *reinterpret_cast<const bf16x8*>(
        &qh[(size_t)(qbw + fr) * HD_ + ks * 32 + fq * 8]);

  // acc[dt][r] = O^T[d = dt*16 + fq*4 + r][q = qbw + fr]
  f32x4 acc[4] = {};
  float mrow = -1e30f, lrow = 0.f;

  const int nt = qtile + 1;  // kv tiles 0 .. qb/64
  int cur = 0;
  const int q0 = 2 * w, q1 = 2 * w + 1;

  // prologue: stage tile 0
  gload16(kh + (size_t)(q0 * 8 + srow) * HD_ + scol, &sK[0][q0 * 512]);
  gload16(kh + (size_t)(q1 * 8 + srow) * HD_ + scol, &sK[0][q1 * 512]);
  gload16(vh + (size_t)(q0 * 8 + srow) * S_ + scol, &sV[0][q0 * 512]);
  gload16(vh + (size_t)(q1 * 8 + srow) * S_ + scol, &sV[0][q1 * 512]);
  __syncthreads();

  for (int t = 0; t < nt; ++t) {
    const int kv0 = t * 64;
    // stage t+1 into the other buffer; latency hides under compute(t)
    if (t + 1 < nt) {
      const int kvn = kv0 + 64;
      gload16(kh + (size_t)(kvn + q0 * 8 + srow) * HD_ + scol,
              &sK[cur ^ 1][q0 * 512]);
      gload16(kh + (size_t)(kvn + q1 * 8 + srow) * HD_ + scol,
              &sK[cur ^ 1][q1 * 512]);
      gload16(vh + (size_t)(q0 * 8 + srow) * S_ + kvn + scol,
              &sV[cur ^ 1][q0 * 512]);
      gload16(vh + (size_t)(q1 * 8 + srow) * S_ + kvn + scol,
              &sV[cur ^ 1][q1 * 512]);
    }

    if (kv0 <= qbw + 15) {  // this warp has unmasked work in this tile
      const char* kb = reinterpret_cast<const char*>(&sK[cur][0]);
      const char* vb = reinterpret_cast<const char*>(&sV[cur][0]);

      // QK^T swapped: s[c][r] = S[kv = kv0+c*16+fq*4+r][q = qbw+fr]
      f32x4 s[4];
      __builtin_amdgcn_s_setprio(1);
#pragma unroll
      for (int c = 0; c < 4; ++c) {
        const int row = c * 16 + fr;
        bf16x8 kf0 = *reinterpret_cast<const bf16x8*>(
            kb + row * 128 + ((fq * 16) ^ swz));
        bf16x8 kf1 = *reinterpret_cast<const bf16x8*>(
            kb + row * 128 + ((fq * 16 + 64) ^ swz));
        f32x4 z = {};
        z = mfma16(kf0, qf[0], z);
        z = mfma16(kf1, qf[1], z);
        s[c] = z;
      }
      __builtin_amdgcn_s_setprio(0);

      if (kv0 + 63 > qbw) {  // tile may contain masked elements
        const int qi = qbw + fr;
#pragma unroll
        for (int c = 0; c < 4; ++c)
#pragma unroll
          for (int r = 0; r < 4; ++r) {
            const int kvi = kv0 + c * 16 + fq * 4 + r;
            if (kvi > qi) s[c][r] = -1e30f;
          }
      }

      // lane-local softmax (q = qbw+fr is lane-local; 2 shfls cross fq)
      float tm = -1e30f;
#pragma unroll
      for (int c = 0; c < 4; ++c)
#pragma unroll
        for (int r = 0; r < 4; ++r) tm = fmaxf(tm, s[c][r]);
      tm = fmaxf(tm, __shfl_xor(tm, 16));
      tm = fmaxf(tm, __shfl_xor(tm, 32));
      const float mn = fmaxf(mrow, tm);
      const float fac = fexp2(mrow - mn);  // log2-domain
      mrow = mn;
      float sum = 0.f;
#pragma unroll
      for (int c = 0; c < 4; ++c) {
        bf16x4 pc;
#pragma unroll
        for (int r = 0; r < 4; ++r) {
          const float p = fexp2(s[c][r] - mn);
          sum += p;
          pc[r] = (__bf16)p;
        }
        const int bo = (c * 32 + fq * 8) ^ swz;
        *reinterpret_cast<bf16x4*>(sPb + fr * 128 + bo) = pc;
      }
      sum += __shfl_xor(sum, 16);
      sum += __shfl_xor(sum, 32);
      lrow = lrow * fac + sum;
#pragma unroll
      for (int dt = 0; dt < 4; ++dt)
#pragma unroll
        for (int r = 0; r < 4; ++r) acc[dt][r] *= fac;

      bf16x8 pa[2];
#pragma unroll
      for (int ks = 0; ks < 2; ++ks) {
        const int bo = (ks * 64 + fq * 16) ^ swz;
        pa[ks] = *reinterpret_cast<const bf16x8*>(sPb + fr * 128 + bo);
      }

      // PV swapped: O^T[d][q] += V^T[d][kv] * P[kv][q]; V from LDS
      __builtin_amdgcn_s_setprio(1);
#pragma unroll
      for (int dt = 0; dt < 4; ++dt) {
        const int row = dt * 16 + fr;
        bf16x8 vf0 = *reinterpret_cast<const bf16x8*>(
            vb + row * 128 + ((fq * 16) ^ swz));
        bf16x8 vf1 = *reinterpret_cast<const bf16x8*>(
            vb + row * 128 + ((fq * 16 + 64) ^ swz));
        acc[dt] = mfma16(vf0, pa[0], acc[dt]);
        acc[dt] = mfma16(vf1, pa[1], acc[dt]);
      }
      __builtin_amdgcn_s_setprio(0);
    }

    __syncthreads();  // all warps done with buf[cur]; stage(t+1) drained
    cur ^= 1;
  }

  // epilogue: all lane-local
  const int b = bh / H_, h = bh % H_;
  const float inv_l = 1.0f / lrow;
  const int qrow = qbw + fr;
#pragma unroll
  for (int dt = 0; dt < 4; ++dt) {
    bf16x4 ov;
#pragma unroll
    for (int r = 0; r < 4; ++r) ov[r] = (__bf16)(acc[dt][r] * inv_l);
    *reinterpret_cast<bf16x4*>(
        &C[((size_t)(b * S_ + qrow)) * D_ + h * HD_ + dt * 16 + fq * 4]) = ov;
  }
}

// ---------------- workspace layout (bf16 elements) ---------------------------
static constexpr size_t XB_OFF = 0;
static constexpr size_t WQ_OFF = XB_OFF + (size_t)T_ * D_;
static constexpr size_t WK_OFF = WQ_OFF + (size_t)D_ * D_;
static constexpr size_t WV_OFF = WK_OFF + (size_t)D_ * D_;
static constexpr size_t WO_OFF = WV_OFF + (size_t)D_ * D_;
static constexpr size_t Q_OFF = WO_OFF + (size_t)D_ * D_;
static constexpr size_t K_OFF = Q_OFF + (size_t)T_ * D_;
static constexpr size_t V_OFF = K_OFF + (size_t)T_ * D_;
static constexpr size_t C_OFF = V_OFF + (size_t)T_ * D_;

extern "C" void kernel_launch(void* const* d_in, const int* in_sizes, int n_in,
                              void* d_out, int out_size, void* d_ws,
                              size_t ws_size, hipStream_t stream) {
  const float* x = (const float*)d_in[0];
  const float* wq = (const float*)d_in[1];
  const float* wk = (const float*)d_in[2];
  const float* wv = (const float*)d_in[3];
  const float* wo = (const float*)d_in[4];
  const float* bo = (const float*)d_in[5];
  float* out = (float*)d_out;
  __bf16* ws = (__bf16*)d_ws;

  __bf16* xb = ws + XB_OFF;
  __bf16* wqb = ws + WQ_OFF;
  __bf16* wkb = ws + WK_OFF;
  __bf16* wvb = ws + WV_OFF;
  __bf16* wob = ws + WO_OFF;
  __bf16* qbuf = ws + Q_OFF;
  __bf16* kbuf = ws + K_OFF;
  __bf16* vbuf = ws + V_OFF;
  __bf16* cbuf = ws + C_OFF;

  {
    constexpr int n4 = T_ * D_ / 4 + 4 * (D_ * D_ / 4);
    cvt_all<<<(n4 + 255) / 256, 256, 0, stream>>>(x, wq, wk, wv, wo, ws);
  }

  gemm_bt<0><<<dim3(64, 18), 256, 0, stream>>>(
      xb, wqb, wkb, wvb, qbuf, kbuf, vbuf, nullptr, nullptr);

  attn_kernel<<<dim3(1536), 256, 0, stream>>>(qbuf, kbuf, vbuf, cbuf);

  gemm_bt<1><<<dim3(64, 6), 256, 0, stream>>>(
      cbuf, wob, nullptr, nullptr, nullptr, nullptr, nullptr, out, bo);
}

// Round 21
// 121.092 us; speedup vs baseline: 1.2230x; 1.0019x over previous
//
#include <hip/hip_runtime.h>

#define B_ 4
#define S_ 2048
#define D_ 768
#define H_ 12
#define HD_ 64
#define T_ (B_ * S_)  // 8192

typedef __bf16 bf16x8 __attribute__((ext_vector_type(8)));
typedef __bf16 bf16x4 __attribute__((ext_vector_type(4)));
typedef float  f32x4  __attribute__((ext_vector_type(4)));

__device__ __forceinline__ f32x4 mfma16(bf16x8 a, bf16x8 b, f32x4 c) {
  return __builtin_amdgcn_mfma_f32_16x16x32_bf16(a, b, c, 0, 0, 0);
}

// 2^x via v_exp_f32 (scores are pre-scaled by log2e at weight-convert time)
__device__ __forceinline__ float fexp2(float x) {
  float r;
  asm("v_exp_f32 %0, %1" : "=v"(r) : "v"(x));
  return r;
}

// async global->LDS, 16B per lane. LDS dest is wave-uniform base + lane*16.
__device__ __forceinline__ void gload16(const __bf16* g, __bf16* lds) {
  __builtin_amdgcn_global_load_lds(
      (__attribute__((address_space(1))) void*)g,
      (__attribute__((address_space(3))) void*)lds, 16, 0, 0);
}

// ---------------- fused fp32 -> bf16 convert (x + 4 weights, 1 launch) -------
__global__ void cvt_all(const float* __restrict__ x,
                        const float* __restrict__ wq,
                        const float* __restrict__ wk,
                        const float* __restrict__ wv,
                        const float* __restrict__ wo,
                        __bf16* __restrict__ out) {
  constexpr int XN4 = T_ * D_ / 4;
  constexpr int WN4 = D_ * D_ / 4;
  const int i = blockIdx.x * blockDim.x + threadIdx.x;
  if (i >= XN4 + 4 * WN4) return;
  const float* src;
  int k;
  float scale = 1.0f;
  if (i < XN4) {
    src = x;
    k = i;
  } else {
    const int j = i - XN4;
    const int wsel = j / WN4;
    k = j - wsel * WN4;
    src = (wsel == 0) ? wq : (wsel == 1) ? wk : (wsel == 2) ? wv : wo;
    if (wsel == 1) scale = 0.18033688f;  // 0.125 * log2(e)
  }
  const float4 v = reinterpret_cast<const float4*>(src)[k];
  bf16x4 o;
  o[0] = (__bf16)(v.x * scale);
  o[1] = (__bf16)(v.y * scale);
  o[2] = (__bf16)(v.z * scale);
  o[3] = (__bf16)(v.w * scale);
  reinterpret_cast<bf16x4*>(out)[i] = o;
}

// ---------------- GEMM: C[m][n] = sum_k A[m][k] * W[n][k]  (B^T layout) ------
// r16-exact (passed, best): 128x128, BK=64, 2-deep counted-vmcnt, swizzled
// LDS, XCD-slab remap, vectorized V^T epilogue.
template <int MODE>
__global__ __launch_bounds__(256)
__attribute__((amdgpu_waves_per_eu(2)))
void gemm_bt(const __bf16* __restrict__ A,
             const __bf16* __restrict__ W0, const __bf16* __restrict__ W1,
             const __bf16* __restrict__ W2,
             __bf16* __restrict__ Oq, __bf16* __restrict__ Ok,
             __bf16* __restrict__ Ov,
             float* __restrict__ fout, const float* __restrict__ bias) {
  constexpr int K = D_;       // 768
  constexpr int NT = K / 64;  // 12 K-tiles
  __shared__ __align__(16) __bf16 sA[2][128 * 64];
  __shared__ __align__(16) __bf16 sB[2][128 * 64];

  const int tid = threadIdx.x;
  const int l = tid & 63;
  const int w = tid >> 6;

  const int flat = blockIdx.y * 64 + blockIdx.x;
  const int xcd = flat & 7;
  const int q = flat >> 3;
  const int mtile = xcd * 8 + (q & 7);
  const int pan = q >> 3;
  const int m0 = mtile * 128;

  int mat, n0;
  const __bf16* Wm;
  if (MODE == 0) {
    mat = pan / 6;
    n0 = (pan % 6) * 128;
    Wm = (mat == 0) ? W0 : (mat == 1) ? W1 : W2;
  } else {
    mat = 0;
    n0 = pan * 128;
    Wm = W0;
  }

  const int srow = l >> 3;                // 0..7
  const int scol = ((l & 7) ^ srow) * 8;  // source col (elements)
  const __bf16* gA[4];
  const __bf16* gB[4];
#pragma unroll
  for (int i = 0; i < 4; ++i) {
    const int c = w * 4 + i;
    gA[i] = A + (size_t)(m0 + c * 8 + srow) * K + scol;
    gB[i] = Wm + (size_t)(n0 + c * 8 + srow) * K + scol;
  }

  f32x4 acc[4][4] = {};
  const int wr = w >> 1, wc = w & 1;
  const int fr = l & 15, fq = l >> 4;
  const int swz = (fr & 7) << 4;

#pragma unroll
  for (int i = 0; i < 4; ++i) {
    const int c = w * 4 + i;
    gload16(gA[i], &sA[0][c * 512]);
    gload16(gB[i], &sB[0][c * 512]);
  }
#pragma unroll
  for (int i = 0; i < 4; ++i) {
    const int c = w * 4 + i;
    gload16(gA[i] + 64, &sA[1][c * 512]);
    gload16(gB[i] + 64, &sB[1][c * 512]);
  }

  int cur = 0;
  for (int kt = 0; kt < NT; ++kt) {
    if (kt + 1 < NT)
      asm volatile("s_waitcnt vmcnt(8)" ::: "memory");
    else
      asm volatile("s_waitcnt vmcnt(0)" ::: "memory");
    __builtin_amdgcn_s_barrier();

    const char* ab = reinterpret_cast<const char*>(&sA[cur][0]);
    const char* bb = reinterpret_cast<const char*>(&sB[cur][0]);
#pragma unroll
    for (int ks = 0; ks < 2; ++ks) {
      bf16x8 af[4], bfr[4];
#pragma unroll
      for (int mi = 0; mi < 4; ++mi)
        af[mi] = *reinterpret_cast<const bf16x8*>(
            ab + (wr * 64 + mi * 16 + fr) * 128 +
            ((ks * 64 + fq * 16) ^ swz));
#pragma unroll
      for (int ni = 0; ni < 4; ++ni)
        bfr[ni] = *reinterpret_cast<const bf16x8*>(
            bb + (wc * 64 + ni * 16 + fr) * 128 +
            ((ks * 64 + fq * 16) ^ swz));
#pragma unroll
      for (int mi = 0; mi < 4; ++mi)
#pragma unroll
        for (int ni = 0; ni < 4; ++ni)
          acc[mi][ni] = mfma16(af[mi], bfr[ni], acc[mi][ni]);
    }
    __builtin_amdgcn_s_barrier();

    if (kt + 2 < NT) {
      const int ko = (kt + 2) * 64;
#pragma unroll
      for (int i = 0; i < 4; ++i) {
        const int c = w * 4 + i;
        gload16(gA[i] + ko, &sA[cur][c * 512]);
        gload16(gB[i] + ko, &sB[cur][c * 512]);
      }
    }
    cur ^= 1;
  }

#pragma unroll
  for (int mi = 0; mi < 4; ++mi) {
    const int mbase = m0 + wr * 64 + mi * 16 + fq * 4;
#pragma unroll
    for (int ni = 0; ni < 4; ++ni) {
      const int o = n0 + wc * 64 + ni * 16 + fr;
      if (MODE == 1) {
#pragma unroll
        for (int r = 0; r < 4; ++r)
          fout[(mbase + r) * D_ + o] = acc[mi][ni][r] + bias[o];
      } else {
        const int h = o >> 6, hd = o & 63;
        const int b = mbase >> 11, s = mbase & (S_ - 1);
        if (mat == 2) {
          bf16x4 vv;
#pragma unroll
          for (int r = 0; r < 4; ++r) vv[r] = (__bf16)acc[mi][ni][r];
          *reinterpret_cast<bf16x4*>(
              &Ov[((size_t)((b * H_ + h) * HD_ + hd)) * S_ + s]) = vv;
        } else {
          __bf16* dst = (mat == 0) ? Oq : Ok;
#pragma unroll
          for (int r = 0; r < 4; ++r)
            dst[((size_t)((b * H_ + h) * S_ + s + r)) * HD_ + hd] =
                (__bf16)acc[mi][ni][r];
        }
      }
    }
  }
}

// ---------------- causal flash attention: 64-q blocks + counted-vmcnt ---------
// r21: r20's 64-q attn entered the STAGING-BOUND regime (405 MB staged at
// ~35 GB/s/CU), but kept the r16 barrier pattern whose __syncthreads drains
// vmcnt(0) — force-completing stage(t+1) with only one compute of cover
// (m233's 2-phase drain stall). Fix: r17's counted-vmcnt pipeline (null then
// — wrong regime; grid-capped): prologue stages t0+t1; loop waits vmcnt(4)
// (own tile landed, next in flight), raw barrier, compute, barrier, stage
// t+2 into freed buffer. vmcnt never drains mid-loop.
__global__ __launch_bounds__(256)
__attribute__((amdgpu_waves_per_eu(4, 4)))
void attn_kernel(const __bf16* __restrict__ Q, const __bf16* __restrict__ Kt,
                 const __bf16* __restrict__ Vt, __bf16* __restrict__ C) {
  __shared__ __align__(16) __bf16 sK[2][64 * 64];  // [kv][hd], swizzled
  __shared__ __align__(16) __bf16 sV[2][64 * 64];  // V^T [hd][kv], swizzled
  __shared__ __align__(16) __bf16 sP[4][16 * 64];  // per-warp P (2 KB)

  const int tid = threadIdx.x;
  const int l = tid & 63;
  const int w = tid >> 6;
  const int fr = l & 15, fq = l >> 4;
  const int bx = blockIdx.x;
  const int xcd = bx & 7;
  const int j = bx >> 3;             // [0, 192)
  const int bh = xcd + 8 * (j % 6);  // head in [0, 48), 6 per XCD
  const int qtile = 31 - j / 6;      // [0, 32), deep first
  const int qb = qtile * 64;
  const int qbw = qb + w * 16;  // this warp's 16 q-rows

  const __bf16* qh = Q + (size_t)bh * S_ * HD_;
  const __bf16* kh = Kt + (size_t)bh * S_ * HD_;
  const __bf16* vh = Vt + (size_t)bh * HD_ * S_;
  char* sPb = reinterpret_cast<char*>(&sP[w][0]);

  const int srow = l >> 3;                       // 0..7
  const int scol = ((l & 7) * 8) ^ (srow << 3);  // pre-swizzled source col
  const int swz = (fr & 7) << 4;                 // read-side XOR (bytes)

  // Q fragment (B-operand): q = qbw + fr, k = ks*32 + fq*8 ..
  bf16x8 qf[2];
#pragma unroll
  for (int ks = 0; ks < 2; ++ks)
    qf[ks] = *reinterpret_cast<const bf16x8*>(
        &qh[(size_t)(qbw + fr) * HD_ + ks * 32 + fq * 8]);

  // acc[dt][r] = O^T[d = dt*16 + fq*4 + r][q = qbw + fr]
  f32x4 acc[4] = {};
  float mrow = -1e30f, lrow = 0.f;

  const int nt = qtile + 1;  // kv tiles 0 .. qb/64
  int cur = 0;
  const int q0 = 2 * w, q1 = 2 * w + 1;

  // prologue: stage tile 0, and tile 1 if it exists (4 loads/warp each)
  gload16(kh + (size_t)(q0 * 8 + srow) * HD_ + scol, &sK[0][q0 * 512]);
  gload16(kh + (size_t)(q1 * 8 + srow) * HD_ + scol, &sK[0][q1 * 512]);
  gload16(vh + (size_t)(q0 * 8 + srow) * S_ + scol, &sV[0][q0 * 512]);
  gload16(vh + (size_t)(q1 * 8 + srow) * S_ + scol, &sV[0][q1 * 512]);
  if (nt > 1) {
    gload16(kh + (size_t)(64 + q0 * 8 + srow) * HD_ + scol, &sK[1][q0 * 512]);
    gload16(kh + (size_t)(64 + q1 * 8 + srow) * HD_ + scol, &sK[1][q1 * 512]);
    gload16(vh + (size_t)(q0 * 8 + srow) * S_ + 64 + scol, &sV[1][q0 * 512]);
    gload16(vh + (size_t)(q1 * 8 + srow) * S_ + 64 + scol, &sV[1][q1 * 512]);
  }

  for (int t = 0; t < nt; ++t) {
    // wait own stage(t) only; stage(t+1)'s 4 loads stay in flight
    if (t + 1 < nt)
      asm volatile("s_waitcnt vmcnt(4)" ::: "memory");
    else
      asm volatile("s_waitcnt vmcnt(0)" ::: "memory");
    __builtin_amdgcn_s_barrier();  // all warps' stage(t) landed

    const int kv0 = t * 64;
    if (kv0 <= qbw + 15) {  // this warp has unmasked work in this tile
      const char* kb = reinterpret_cast<const char*>(&sK[cur][0]);
      const char* vb = reinterpret_cast<const char*>(&sV[cur][0]);

      // QK^T swapped: s[c][r] = S[kv = kv0+c*16+fq*4+r][q = qbw+fr]
      f32x4 s[4];
      __builtin_amdgcn_s_setprio(1);
#pragma unroll
      for (int c = 0; c < 4; ++c) {
        const int row = c * 16 + fr;
        bf16x8 kf0 = *reinterpret_cast<const bf16x8*>(
            kb + row * 128 + ((fq * 16) ^ swz));
        bf16x8 kf1 = *reinterpret_cast<const bf16x8*>(
            kb + row * 128 + ((fq * 16 + 64) ^ swz));
        f32x4 z = {};
        z = mfma16(kf0, qf[0], z);
        z = mfma16(kf1, qf[1], z);
        s[c] = z;
      }
      __builtin_amdgcn_s_setprio(0);

      if (kv0 + 63 > qbw) {  // tile may contain masked elements
        const int qi = qbw + fr;
#pragma unroll
        for (int c = 0; c < 4; ++c)
#pragma unroll
          for (int r = 0; r < 4; ++r) {
            const int kvi = kv0 + c * 16 + fq * 4 + r;
            if (kvi > qi) s[c][r] = -1e30f;
          }
      }

      // lane-local softmax (q = qbw+fr is lane-local; 2 shfls cross fq)
      float tm = -1e30f;
#pragma unroll
      for (int c = 0; c < 4; ++c)
#pragma unroll
        for (int r = 0; r < 4; ++r) tm = fmaxf(tm, s[c][r]);
      tm = fmaxf(tm, __shfl_xor(tm, 16));
      tm = fmaxf(tm, __shfl_xor(tm, 32));
      const float mn = fmaxf(mrow, tm);
      const float fac = fexp2(mrow - mn);  // log2-domain
      mrow = mn;
      float sum = 0.f;
#pragma unroll
      for (int c = 0; c < 4; ++c) {
        bf16x4 pc;
#pragma unroll
        for (int r = 0; r < 4; ++r) {
          const float p = fexp2(s[c][r] - mn);
          sum += p;
          pc[r] = (__bf16)p;
        }
        const int bo = (c * 32 + fq * 8) ^ swz;
        *reinterpret_cast<bf16x4*>(sPb + fr * 128 + bo) = pc;
      }
      sum += __shfl_xor(sum, 16);
      sum += __shfl_xor(sum, 32);
      lrow = lrow * fac + sum;
#pragma unroll
      for (int dt = 0; dt < 4; ++dt)
#pragma unroll
        for (int r = 0; r < 4; ++r) acc[dt][r] *= fac;

      bf16x8 pa[2];
#pragma unroll
      for (int ks = 0; ks < 2; ++ks) {
        const int bo = (ks * 64 + fq * 16) ^ swz;
        pa[ks] = *reinterpret_cast<const bf16x8*>(sPb + fr * 128 + bo);
      }

      // PV swapped: O^T[d][q] += V^T[d][kv] * P[kv][q]; V from LDS
      __builtin_amdgcn_s_setprio(1);
#pragma unroll
      for (int dt = 0; dt < 4; ++dt) {
        const int row = dt * 16 + fr;
        bf16x8 vf0 = *reinterpret_cast<const bf16x8*>(
            vb + row * 128 + ((fq * 16) ^ swz));
        bf16x8 vf1 = *reinterpret_cast<const bf16x8*>(
            vb + row * 128 + ((fq * 16 + 64) ^ swz));
        acc[dt] = mfma16(vf0, pa[0], acc[dt]);
        acc[dt] = mfma16(vf1, pa[1], acc[dt]);
      }
      __builtin_amdgcn_s_setprio(0);
    }

    __builtin_amdgcn_s_barrier();  // all warps done reading buf[cur]

    // stage tile t+2 into the buffer just freed (2-deep pipeline)
    if (t + 2 < nt) {
      const int kvn = (t + 2) * 64;
      gload16(kh + (size_t)(kvn + q0 * 8 + srow) * HD_ + scol,
              &sK[cur][q0 * 512]);
      gload16(kh + (size_t)(kvn + q1 * 8 + srow) * HD_ + scol,
              &sK[cur][q1 * 512]);
      gload16(vh + (size_t)(q0 * 8 + srow) * S_ + kvn + scol,
              &sV[cur][q0 * 512]);
      gload16(vh + (size_t)(q1 * 8 + srow) * S_ + kvn + scol,
              &sV[cur][q1 * 512]);
    }
    cur ^= 1;
  }

  // epilogue: all lane-local
  const int b = bh / H_, h = bh % H_;
  const float inv_l = 1.0f / lrow;
  const int qrow = qbw + fr;
#pragma unroll
  for (int dt = 0; dt < 4; ++dt) {
    bf16x4 ov;
#pragma unroll
    for (int r = 0; r < 4; ++r) ov[r] = (__bf16)(acc[dt][r] * inv_l);
    *reinterpret_cast<bf16x4*>(
        &C[((size_t)(b * S_ + qrow)) * D_ + h * HD_ + dt * 16 + fq * 4]) = ov;
  }
}

// ---------------- workspace layout (bf16 elements) ---------------------------
static constexpr size_t XB_OFF = 0;
static constexpr size_t WQ_OFF = XB_OFF + (size_t)T_ * D_;
static constexpr size_t WK_OFF = WQ_OFF + (size_t)D_ * D_;
static constexpr size_t WV_OFF = WK_OFF + (size_t)D_ * D_;
static constexpr size_t WO_OFF = WV_OFF + (size_t)D_ * D_;
static constexpr size_t Q_OFF = WO_OFF + (size_t)D_ * D_;
static constexpr size_t K_OFF = Q_OFF + (size_t)T_ * D_;
static constexpr size_t V_OFF = K_OFF + (size_t)T_ * D_;
static constexpr size_t C_OFF = V_OFF + (size_t)T_ * D_;

extern "C" void kernel_launch(void* const* d_in, const int* in_sizes, int n_in,
                              void* d_out, int out_size, void* d_ws,
                              size_t ws_size, hipStream_t stream) {
  const float* x = (const float*)d_in[0];
  const float* wq = (const float*)d_in[1];
  const float* wk = (const float*)d_in[2];
  const float* wv = (const float*)d_in[3];
  const float* wo = (const float*)d_in[4];
  const float* bo = (const float*)d_in[5];
  float* out = (float*)d_out;
  __bf16* ws = (__bf16*)d_ws;

  __bf16* xb = ws + XB_OFF;
  __bf16* wqb = ws + WQ_OFF;
  __bf16* wkb = ws + WK_OFF;
  __bf16* wvb = ws + WV_OFF;
  __bf16* wob = ws + WO_OFF;
  __bf16* qbuf = ws + Q_OFF;
  __bf16* kbuf = ws + K_OFF;
  __bf16* vbuf = ws + V_OFF;
  __bf16* cbuf = ws + C_OFF;

  {
    constexpr int n4 = T_ * D_ / 4 + 4 * (D_ * D_ / 4);
    cvt_all<<<(n4 + 255) / 256, 256, 0, stream>>>(x, wq, wk, wv, wo, ws);
  }

  gemm_bt<0><<<dim3(64, 18), 256, 0, stream>>>(
      xb, wqb, wkb, wvb, qbuf, kbuf, vbuf, nullptr, nullptr);

  attn_kernel<<<dim3(1536), 256, 0, stream>>>(qbuf, kbuf, vbuf, cbuf);

  gemm_bt<1><<<dim3(64, 6), 256, 0, stream>>>(
      cbuf, wob, nullptr, nullptr, nullptr, nullptr, nullptr, out, bo);
}

// Round 22
// 117.744 us; speedup vs baseline: 1.2578x; 1.0284x over previous
//
#include <hip/hip_runtime.h>

#define B_ 4
#define S_ 2048
#define D_ 768
#define H_ 12
#define HD_ 64
#define T_ (B_ * S_)  // 8192

typedef __bf16 bf16x8 __attribute__((ext_vector_type(8)));
typedef __bf16 bf16x4 __attribute__((ext_vector_type(4)));
typedef float  f32x4  __attribute__((ext_vector_type(4)));

__device__ __forceinline__ f32x4 mfma16(bf16x8 a, bf16x8 b, f32x4 c) {
  return __builtin_amdgcn_mfma_f32_16x16x32_bf16(a, b, c, 0, 0, 0);
}

// 2^x via v_exp_f32 (scores are pre-scaled by log2e at weight-convert time)
__device__ __forceinline__ float fexp2(float x) {
  float r;
  asm("v_exp_f32 %0, %1" : "=v"(r) : "v"(x));
  return r;
}

// async global->LDS, 16B per lane. LDS dest is wave-uniform base + lane*16.
__device__ __forceinline__ void gload16(const __bf16* g, __bf16* lds) {
  __builtin_amdgcn_global_load_lds(
      (__attribute__((address_space(1))) void*)g,
      (__attribute__((address_space(3))) void*)lds, 16, 0, 0);
}

// ---------------- fused fp32 -> bf16 convert (x + 4 weights, 1 launch) -------
__global__ void cvt_all(const float* __restrict__ x,
                        const float* __restrict__ wq,
                        const float* __restrict__ wk,
                        const float* __restrict__ wv,
                        const float* __restrict__ wo,
                        __bf16* __restrict__ out) {
  constexpr int XN4 = T_ * D_ / 4;
  constexpr int WN4 = D_ * D_ / 4;
  const int i = blockIdx.x * blockDim.x + threadIdx.x;
  if (i >= XN4 + 4 * WN4) return;
  const float* src;
  int k;
  float scale = 1.0f;
  if (i < XN4) {
    src = x;
    k = i;
  } else {
    const int j = i - XN4;
    const int wsel = j / WN4;
    k = j - wsel * WN4;
    src = (wsel == 0) ? wq : (wsel == 1) ? wk : (wsel == 2) ? wv : wo;
    if (wsel == 1) scale = 0.18033688f;  // 0.125 * log2(e)
  }
  const float4 v = reinterpret_cast<const float4*>(src)[k];
  bf16x4 o;
  o[0] = (__bf16)(v.x * scale);
  o[1] = (__bf16)(v.y * scale);
  o[2] = (__bf16)(v.z * scale);
  o[3] = (__bf16)(v.w * scale);
  reinterpret_cast<bf16x4*>(out)[i] = o;
}

// ---------------- GEMM: C[m][n] = sum_k A[m][k] * W[n][k]  (B^T layout) ------
// r16/r21 hot loop (128x128, BK=64, 2-deep counted-vmcnt, swizzled LDS,
// XCD-slab remap). r22 change: LDS-TRANSPOSE EPILOGUE — after the K-loop the
// 64 KB LDS is dead; each wave dumps its 64x64 f32 fragment into a private
// 16 KB region and reads back row-contiguous, so Q/K store as 8-B bf16x4
// row segments (128 B contiguous per 16 lanes) and MODE1 as 16-B float4
// (+bias), instead of 4x column-scattered 2-B/4-B stores (r21: gemm0's
// dominant cost; V^T vectorization alone was 81->62 us).
template <int MODE>
__global__ __launch_bounds__(256)
__attribute__((amdgpu_waves_per_eu(2)))
void gemm_bt(const __bf16* __restrict__ A,
             const __bf16* __restrict__ W0, const __bf16* __restrict__ W1,
             const __bf16* __restrict__ W2,
             __bf16* __restrict__ Oq, __bf16* __restrict__ Ok,
             __bf16* __restrict__ Ov,
             float* __restrict__ fout, const float* __restrict__ bias) {
  constexpr int K = D_;       // 768
  constexpr int NT = K / 64;  // 12 K-tiles
  __shared__ __align__(16) char smem[65536];  // loop: sA|sB; epilogue: f32 x4
  __bf16* sA0 = reinterpret_cast<__bf16*>(smem);          // [2][128*64]
  __bf16* sB0 = reinterpret_cast<__bf16*>(smem + 32768);  // [2][128*64]

  const int tid = threadIdx.x;
  const int l = tid & 63;
  const int w = tid >> 6;

  const int flat = blockIdx.y * 64 + blockIdx.x;
  const int xcd = flat & 7;
  const int q = flat >> 3;
  const int mtile = xcd * 8 + (q & 7);
  const int pan = q >> 3;
  const int m0 = mtile * 128;

  int mat, n0;
  const __bf16* Wm;
  if (MODE == 0) {
    mat = pan / 6;
    n0 = (pan % 6) * 128;
    Wm = (mat == 0) ? W0 : (mat == 1) ? W1 : W2;
  } else {
    mat = 0;
    n0 = pan * 128;
    Wm = W0;
  }

  const int srow = l >> 3;                // 0..7
  const int scol = ((l & 7) ^ srow) * 8;  // source col (elements)
  const __bf16* gA[4];
  const __bf16* gB[4];
#pragma unroll
  for (int i = 0; i < 4; ++i) {
    const int c = w * 4 + i;
    gA[i] = A + (size_t)(m0 + c * 8 + srow) * K + scol;
    gB[i] = Wm + (size_t)(n0 + c * 8 + srow) * K + scol;
  }

  f32x4 acc[4][4] = {};
  const int wr = w >> 1, wc = w & 1;
  const int fr = l & 15, fq = l >> 4;
  const int swz = (fr & 7) << 4;

#pragma unroll
  for (int i = 0; i < 4; ++i) {
    const int c = w * 4 + i;
    gload16(gA[i], &sA0[c * 512]);
    gload16(gB[i], &sB0[c * 512]);
  }
#pragma unroll
  for (int i = 0; i < 4; ++i) {
    const int c = w * 4 + i;
    gload16(gA[i] + 64, &sA0[8192 + c * 512]);
    gload16(gB[i] + 64, &sB0[8192 + c * 512]);
  }

  int cur = 0;
  for (int kt = 0; kt < NT; ++kt) {
    if (kt + 1 < NT)
      asm volatile("s_waitcnt vmcnt(8)" ::: "memory");
    else
      asm volatile("s_waitcnt vmcnt(0)" ::: "memory");
    __builtin_amdgcn_s_barrier();

    const char* ab = reinterpret_cast<const char*>(&sA0[cur * 8192]);
    const char* bb = reinterpret_cast<const char*>(&sB0[cur * 8192]);
#pragma unroll
    for (int ks = 0; ks < 2; ++ks) {
      bf16x8 af[4], bfr[4];
#pragma unroll
      for (int mi = 0; mi < 4; ++mi)
        af[mi] = *reinterpret_cast<const bf16x8*>(
            ab + (wr * 64 + mi * 16 + fr) * 128 +
            ((ks * 64 + fq * 16) ^ swz));
#pragma unroll
      for (int ni = 0; ni < 4; ++ni)
        bfr[ni] = *reinterpret_cast<const bf16x8*>(
            bb + (wc * 64 + ni * 16 + fr) * 128 +
            ((ks * 64 + fq * 16) ^ swz));
#pragma unroll
      for (int mi = 0; mi < 4; ++mi)
#pragma unroll
        for (int ni = 0; ni < 4; ++ni)
          acc[mi][ni] = mfma16(af[mi], bfr[ni], acc[mi][ni]);
    }
    __builtin_amdgcn_s_barrier();

    if (kt + 2 < NT) {
      const int ko = (kt + 2) * 64;
#pragma unroll
      for (int i = 0; i < 4; ++i) {
        const int c = w * 4 + i;
        gload16(gA[i] + ko, &sA0[cur * 8192 + c * 512]);
        gload16(gB[i] + ko, &sB0[cur * 8192 + c * 512]);
      }
    }
    cur ^= 1;
  }

  // ---------------- epilogue ----------------
  if (MODE == 0 && mat == 2) {
    // V^T: direct vectorized store (4 consecutive s per lane -> one 8B store)
#pragma unroll
    for (int mi = 0; mi < 4; ++mi) {
      const int mbase = m0 + wr * 64 + mi * 16 + fq * 4;
      const int b = mbase >> 11, s = mbase & (S_ - 1);
#pragma unroll
      for (int ni = 0; ni < 4; ++ni) {
        const int o = n0 + wc * 64 + ni * 16 + fr;
        const int h = o >> 6, hd = o & 63;
        bf16x4 vv;
#pragma unroll
        for (int r = 0; r < 4; ++r) vv[r] = (__bf16)acc[mi][ni][r];
        *reinterpret_cast<bf16x4*>(
            &Ov[((size_t)((b * H_ + h) * HD_ + hd)) * S_ + s]) = vv;
      }
    }
  } else {
    // LDS transpose: wave-private [64][64] f32 region (16 KB each)
    float* fW = reinterpret_cast<float*>(smem) + w * 4096;
#pragma unroll
    for (int mi = 0; mi < 4; ++mi)
#pragma unroll
      for (int ni = 0; ni < 4; ++ni)
#pragma unroll
        for (int r = 0; r < 4; ++r)
          fW[(mi * 16 + fq * 4 + r) * 64 + ni * 16 + fr] = acc[mi][ni][r];
    // per-wave region: no barrier needed (lgkmcnt ordering is per-wave)
    if (MODE == 1) {
      const int ocol = n0 + wc * 64 + fr * 4;
      const float4 bs = *reinterpret_cast<const float4*>(&bias[ocol]);
#pragma unroll
      for (int it = 0; it < 16; ++it) {
        const int lrow = it * 4 + fq;
        f32x4 v = *reinterpret_cast<const f32x4*>(&fW[lrow * 64 + fr * 4]);
        v[0] += bs.x;
        v[1] += bs.y;
        v[2] += bs.z;
        v[3] += bs.w;
        *reinterpret_cast<f32x4*>(
            &fout[(size_t)(m0 + wr * 64 + lrow) * D_ + ocol]) = v;
      }
    } else {
      const int o = n0 + wc * 64;  // 64-aligned -> h const, hd = lcol
      const int h = o >> 6;
      __bf16* dst = (mat == 0) ? Oq : Ok;
#pragma unroll
      for (int it = 0; it < 16; ++it) {
        const int lrow = it * 4 + fq;
        const int m = m0 + wr * 64 + lrow;
        const int b = m >> 11, s = m & (S_ - 1);
        const f32x4 v =
            *reinterpret_cast<const f32x4*>(&fW[lrow * 64 + fr * 4]);
        bf16x4 ov;
#pragma unroll
        for (int r = 0; r < 4; ++r) ov[r] = (__bf16)v[r];
        *reinterpret_cast<bf16x4*>(
            &dst[((size_t)((b * H_ + h) * S_ + s)) * HD_ + fr * 4]) = ov;
      }
    }
  }
}

// ---------------- causal flash attention: 64-q blocks + counted-vmcnt ---------
// (r21-exact, passed)
__global__ __launch_bounds__(256)
__attribute__((amdgpu_waves_per_eu(4, 4)))
void attn_kernel(const __bf16* __restrict__ Q, const __bf16* __restrict__ Kt,
                 const __bf16* __restrict__ Vt, __bf16* __restrict__ C) {
  __shared__ __align__(16) __bf16 sK[2][64 * 64];  // [kv][hd], swizzled
  __shared__ __align__(16) __bf16 sV[2][64 * 64];  // V^T [hd][kv], swizzled
  __shared__ __align__(16) __bf16 sP[4][16 * 64];  // per-warp P (2 KB)

  const int tid = threadIdx.x;
  const int l = tid & 63;
  const int w = tid >> 6;
  const int fr = l & 15, fq = l >> 4;
  const int bx = blockIdx.x;
  const int xcd = bx & 7;
  const int j = bx >> 3;             // [0, 192)
  const int bh = xcd + 8 * (j % 6);  // head in [0, 48), 6 per XCD
  const int qtile = 31 - j / 6;      // [0, 32), deep first
  const int qb = qtile * 64;
  const int qbw = qb + w * 16;  // this warp's 16 q-rows

  const __bf16* qh = Q + (size_t)bh * S_ * HD_;
  const __bf16* kh = Kt + (size_t)bh * S_ * HD_;
  const __bf16* vh = Vt + (size_t)bh * HD_ * S_;
  char* sPb = reinterpret_cast<char*>(&sP[w][0]);

  const int srow = l >> 3;                       // 0..7
  const int scol = ((l & 7) * 8) ^ (srow << 3);  // pre-swizzled source col
  const int swz = (fr & 7) << 4;                 // read-side XOR (bytes)

  bf16x8 qf[2];
#pragma unroll
  for (int ks = 0; ks < 2; ++ks)
    qf[ks] = *reinterpret_cast<const bf16x8*>(
        &qh[(size_t)(qbw + fr) * HD_ + ks * 32 + fq * 8]);

  f32x4 acc[4] = {};
  float mrow = -1e30f, lrow = 0.f;

  const int nt = qtile + 1;  // kv tiles 0 .. qb/64
  int cur = 0;
  const int q0 = 2 * w, q1 = 2 * w + 1;

  gload16(kh + (size_t)(q0 * 8 + srow) * HD_ + scol, &sK[0][q0 * 512]);
  gload16(kh + (size_t)(q1 * 8 + srow) * HD_ + scol, &sK[0][q1 * 512]);
  gload16(vh + (size_t)(q0 * 8 + srow) * S_ + scol, &sV[0][q0 * 512]);
  gload16(vh + (size_t)(q1 * 8 + srow) * S_ + scol, &sV[0][q1 * 512]);
  if (nt > 1) {
    gload16(kh + (size_t)(64 + q0 * 8 + srow) * HD_ + scol, &sK[1][q0 * 512]);
    gload16(kh + (size_t)(64 + q1 * 8 + srow) * HD_ + scol, &sK[1][q1 * 512]);
    gload16(vh + (size_t)(q0 * 8 + srow) * S_ + 64 + scol, &sV[1][q0 * 512]);
    gload16(vh + (size_t)(q1 * 8 + srow) * S_ + 64 + scol, &sV[1][q1 * 512]);
  }

  for (int t = 0; t < nt; ++t) {
    if (t + 1 < nt)
      asm volatile("s_waitcnt vmcnt(4)" ::: "memory");
    else
      asm volatile("s_waitcnt vmcnt(0)" ::: "memory");
    __builtin_amdgcn_s_barrier();  // all warps' stage(t) landed

    const int kv0 = t * 64;
    if (kv0 <= qbw + 15) {
      const char* kb = reinterpret_cast<const char*>(&sK[cur][0]);
      const char* vb = reinterpret_cast<const char*>(&sV[cur][0]);

      f32x4 s[4];
      __builtin_amdgcn_s_setprio(1);
#pragma unroll
      for (int c = 0; c < 4; ++c) {
        const int row = c * 16 + fr;
        bf16x8 kf0 = *reinterpret_cast<const bf16x8*>(
            kb + row * 128 + ((fq * 16) ^ swz));
        bf16x8 kf1 = *reinterpret_cast<const bf16x8*>(
            kb + row * 128 + ((fq * 16 + 64) ^ swz));
        f32x4 z = {};
        z = mfma16(kf0, qf[0], z);
        z = mfma16(kf1, qf[1], z);
        s[c] = z;
      }
      __builtin_amdgcn_s_setprio(0);

      if (kv0 + 63 > qbw) {
        const int qi = qbw + fr;
#pragma unroll
        for (int c = 0; c < 4; ++c)
#pragma unroll
          for (int r = 0; r < 4; ++r) {
            const int kvi = kv0 + c * 16 + fq * 4 + r;
            if (kvi > qi) s[c][r] = -1e30f;
          }
      }

      float tm = -1e30f;
#pragma unroll
      for (int c = 0; c < 4; ++c)
#pragma unroll
        for (int r = 0; r < 4; ++r) tm = fmaxf(tm, s[c][r]);
      tm = fmaxf(tm, __shfl_xor(tm, 16));
      tm = fmaxf(tm, __shfl_xor(tm, 32));
      const float mn = fmaxf(mrow, tm);
      const float fac = fexp2(mrow - mn);  // log2-domain
      mrow = mn;
      float sum = 0.f;
#pragma unroll
      for (int c = 0; c < 4; ++c) {
        bf16x4 pc;
#pragma unroll
        for (int r = 0; r < 4; ++r) {
          const float p = fexp2(s[c][r] - mn);
          sum += p;
          pc[r] = (__bf16)p;
        }
        const int bo = (c * 32 + fq * 8) ^ swz;
        *reinterpret_cast<bf16x4*>(sPb + fr * 128 + bo) = pc;
      }
      sum += __shfl_xor(sum, 16);
      sum += __shfl_xor(sum, 32);
      lrow = lrow * fac + sum;
#pragma unroll
      for (int dt = 0; dt < 4; ++dt)
#pragma unroll
        for (int r = 0; r < 4; ++r) acc[dt][r] *= fac;

      bf16x8 pa[2];
#pragma unroll
      for (int ks = 0; ks < 2; ++ks) {
        const int bo = (ks * 64 + fq * 16) ^ swz;
        pa[ks] = *reinterpret_cast<const bf16x8*>(sPb + fr * 128 + bo);
      }

      __builtin_amdgcn_s_setprio(1);
#pragma unroll
      for (int dt = 0; dt < 4; ++dt) {
        const int row = dt * 16 + fr;
        bf16x8 vf0 = *reinterpret_cast<const bf16x8*>(
            vb + row * 128 + ((fq * 16) ^ swz));
        bf16x8 vf1 = *reinterpret_cast<const bf16x8*>(
            vb + row * 128 + ((fq * 16 + 64) ^ swz));
        acc[dt] = mfma16(vf0, pa[0], acc[dt]);
        acc[dt] = mfma16(vf1, pa[1], acc[dt]);
      }
      __builtin_amdgcn_s_setprio(0);
    }

    __builtin_amdgcn_s_barrier();  // all warps done reading buf[cur]

    if (t + 2 < nt) {
      const int kvn = (t + 2) * 64;
      gload16(kh + (size_t)(kvn + q0 * 8 + srow) * HD_ + scol,
              &sK[cur][q0 * 512]);
      gload16(kh + (size_t)(kvn + q1 * 8 + srow) * HD_ + scol,
              &sK[cur][q1 * 512]);
      gload16(vh + (size_t)(q0 * 8 + srow) * S_ + kvn + scol,
              &sV[cur][q0 * 512]);
      gload16(vh + (size_t)(q1 * 8 + srow) * S_ + kvn + scol,
              &sV[cur][q1 * 512]);
    }
    cur ^= 1;
  }

  const int b = bh / H_, h = bh % H_;
  const float inv_l = 1.0f / lrow;
  const int qrow = qbw + fr;
#pragma unroll
  for (int dt = 0; dt < 4; ++dt) {
    bf16x4 ov;
#pragma unroll
    for (int r = 0; r < 4; ++r) ov[r] = (__bf16)(acc[dt][r] * inv_l);
    *reinterpret_cast<bf16x4*>(
        &C[((size_t)(b * S_ + qrow)) * D_ + h * HD_ + dt * 16 + fq * 4]) = ov;
  }
}

// ---------------- workspace layout (bf16 elements) ---------------------------
static constexpr size_t XB_OFF = 0;
static constexpr size_t WQ_OFF = XB_OFF + (size_t)T_ * D_;
static constexpr size_t WK_OFF = WQ_OFF + (size_t)D_ * D_;
static constexpr size_t WV_OFF = WK_OFF + (size_t)D_ * D_;
static constexpr size_t WO_OFF = WV_OFF + (size_t)D_ * D_;
static constexpr size_t Q_OFF = WO_OFF + (size_t)D_ * D_;
static constexpr size_t K_OFF = Q_OFF + (size_t)T_ * D_;
static constexpr size_t V_OFF = K_OFF + (size_t)T_ * D_;
static constexpr size_t C_OFF = V_OFF + (size_t)T_ * D_;

extern "C" void kernel_launch(void* const* d_in, const int* in_sizes, int n_in,
                              void* d_out, int out_size, void* d_ws,
                              size_t ws_size, hipStream_t stream) {
  const float* x = (const float*)d_in[0];
  const float* wq = (const float*)d_in[1];
  const float* wk = (const float*)d_in[2];
  const float* wv = (const float*)d_in[3];
  const float* wo = (const float*)d_in[4];
  const float* bo = (const float*)d_in[5];
  float* out = (float*)d_out;
  __bf16* ws = (__bf16*)d_ws;

  __bf16* xb = ws + XB_OFF;
  __bf16* wqb = ws + WQ_OFF;
  __bf16* wkb = ws + WK_OFF;
  __bf16* wvb = ws + WV_OFF;
  __bf16* wob = ws + WO_OFF;
  __bf16* qbuf = ws + Q_OFF;
  __bf16* kbuf = ws + K_OFF;
  __bf16* vbuf = ws + V_OFF;
  __bf16* cbuf = ws + C_OFF;

  {
    constexpr int n4 = T_ * D_ / 4 + 4 * (D_ * D_ / 4);
    cvt_all<<<(n4 + 255) / 256, 256, 0, stream>>>(x, wq, wk, wv, wo, ws);
  }

  gemm_bt<0><<<dim3(64, 18), 256, 0, stream>>>(
      xb, wqb, wkb, wvb, qbuf, kbuf, vbuf, nullptr, nullptr);

  attn_kernel<<<dim3(1536), 256, 0, stream>>>(qbuf, kbuf, vbuf, cbuf);

  gemm_bt<1><<<dim3(64, 6), 256, 0, stream>>>(
      cbuf, wob, nullptr, nullptr, nullptr, nullptr, nullptr, out, bo);
}